// Round 17
// baseline (249.234 us; speedup 1.0000x reference)
//
#include <hip/hip_runtime.h>
#include <hip/hip_bf16.h>
#include <stdint.h>

// Problem constants
// B=2 S=2048 HID=2560 H=8 HKV=4 D=256 GROUPS=2 window=512
#define QSCALE 0.09016844005555459f  // (1/16) * log2(e)

typedef __attribute__((ext_vector_type(4))) float f32x4;
typedef __attribute__((ext_vector_type(8))) __bf16 bf16x8;
typedef __attribute__((ext_vector_type(8))) unsigned short ushort8;

static __device__ __forceinline__ float bf2f(unsigned short v) {
  union { unsigned u; float f; } x; x.u = ((unsigned)v) << 16; return x.f;
}
static __device__ __forceinline__ unsigned short f2bf(float f) {
  union { float f; unsigned u; } x; x.f = f;
  unsigned r = x.u + 0x7fffu + ((x.u >> 16) & 1u);
  return (unsigned short)(r >> 16);
}
static __device__ __forceinline__ void gload16(const void* g, void* l) {
  __builtin_amdgcn_global_load_lds((const __attribute__((address_space(1))) void*)g,
                                   (__attribute__((address_space(3))) void*)l, 16, 0, 0);
}
#define SBAR() __builtin_amdgcn_s_barrier()

// ---------------- rope table: ct/st[s][j], j=0..127 ----------------
__global__ __launch_bounds__(256) void k_rope_tab(const int* __restrict__ pos,
                                                  float* __restrict__ ct,
                                                  float* __restrict__ st) {
  int idx = blockIdx.x * 256 + threadIdx.x;  // S*128 = 262144 exact
  int s = idx >> 7, j = idx & 127;
  float inv = exp2f((float)j * (-13.287712379549449f / 128.0f));  // 10000^(-j/128)
  float ang = (float)pos[s] * inv;
  float sv, cv;
  sincosf(ang, &sv, &cv);
  ct[idx] = cv; st[idx] = sv;
}

// ---------------- fp32 -> bf16 elementwise (vectorized) ----------------
__global__ __launch_bounds__(256) void k_cvt_bf16(const float* __restrict__ in,
                                                  unsigned short* __restrict__ out, int n4) {
  int i = blockIdx.x * 256 + threadIdx.x;
  if (i >= n4) return;
  float4 v = ((const float4*)in)[i];
  ushort4 o; o.x = f2bf(v.x); o.y = f2bf(v.y); o.z = f2bf(v.z); o.w = f2bf(v.w);
  ((ushort4*)out)[i] = o;
}

// ---------------- transpose fp32 [R][C] -> bf16 [C][R] ----------------
__global__ __launch_bounds__(256) void k_transpose_w(const float* __restrict__ in,
                                                     unsigned short* __restrict__ out,
                                                     int R, int C) {
  __shared__ float tile[32][33];
  int c0 = blockIdx.x * 32, r0 = blockIdx.y * 32;
  int tx = threadIdx.x & 31, ty = threadIdx.x >> 5;  // 32 x 8
#pragma unroll
  for (int i = 0; i < 4; i++)
    tile[ty + 8*i][tx] = in[(size_t)(r0 + ty + 8*i) * C + c0 + tx];
  __syncthreads();
#pragma unroll
  for (int i = 0; i < 4; i++)
    out[(size_t)(c0 + ty + 8*i) * R + r0 + tx] = f2bf(tile[tx][ty + 8*i]);
}

// ---------------- 256x256 bf16 GEMM (r10 structure — best measured, FINAL) ----------------
// BK=32, ring of 4 LDS slots (128KB), 8 waves (2Mx4N), counted vmcnt(8) (never
// 0 mid-loop), ONE raw s_barrier per K-step, setprio around the 32-MFMA cluster.
// Ledger: RAW: entering step kt, tile kt in LDS for ALL waves (tail of kt-1 did
// vmcnt(8) + SBAR). WAR: stage(kt+3) -> slot (kt-1)&3; readers were step kt-1's
// ds_reads, complete before its MFMA (lgkm) which precedes the tail SBAR.
// Bank swizzle (verified 0-conflict): chunk ^= (row>>1)&3, inverse-swizzled
// GLOBAL source + swizzled ds_read (rule #21). Requires nt % 4 == 0, nt >= 8.
template <bool F32OUT>
__global__ __launch_bounds__(512, 1) void k_gemm256(const unsigned short* __restrict__ A,
                                                    const unsigned short* __restrict__ Bt,
                                                    void* __restrict__ Cm,
                                                    int M, int N, int K) {
  __shared__ __align__(16) unsigned short ldsA[4][8192];  // 4 slots x [256][32] bf16 (swizzled)
  __shared__ __align__(16) unsigned short ldsB[4][8192];
  const int nbn = N >> 8;
  int bid = blockIdx.x;
  int nwg = gridDim.x;
  if ((nwg & 7) == 0) {                    // XCD-aware swizzle (bijective: nwg%8==0)
    int cpx = nwg >> 3;
    bid = (bid & 7) * cpx + (bid >> 3);
  }
  const int bm = bid / nbn, bn = bid % nbn;
  const int tid = threadIdx.x;
  const int w = tid >> 6, l = tid & 63;
  const int wm = w >> 2, wn = w & 3;
  const int lr = l & 15, lk = l >> 4;
  const int nt = K >> 5;                   // BK = 32; nt % 4 == 0, nt >= 8

  const int rL = tid >> 2;
  const int swc = ((tid & 3) ^ ((tid >> 3) & 3)) << 3;
  const unsigned short* Ag = A + (size_t)(bm * 256 + rL) * K + swc;
  const unsigned short* Bg = Bt + (size_t)(bn * 256 + rL) * K + swc;
  const int ldsoff = w * 512;
  const int wb = ((lk ^ ((lr >> 1) & 3)) << 3);
  const int arow0 = wm * 128 + lr;
  const int brow0 = wn * 64 + lr;

  f32x4 acc[8][4] = {};

#define STAGE_A(kt_, s_) do { \
    gload16(Ag + (size_t)(kt_) * 32,                    (char*)&ldsA[s_][ldsoff]); \
    gload16(Ag + (size_t)(kt_) * 32 + (size_t)128 * K,  (char*)&ldsA[s_][4096 + ldsoff]); } while (0)
#define STAGE_B(kt_, s_) do { \
    gload16(Bg + (size_t)(kt_) * 32,                    (char*)&ldsB[s_][ldsoff]); \
    gload16(Bg + (size_t)(kt_) * 32 + (size_t)128 * K,  (char*)&ldsB[s_][4096 + ldsoff]); } while (0)

#define KSTEP(kt_, S_, PF_, VMC_, TAILBAR_) do { \
    bf16x8 af[8], bf[4]; \
    _Pragma("unroll") \
    for (int i = 0; i < 8; ++i) \
      af[i] = *(const bf16x8*)&ldsA[S_][((arow0 + i * 16) << 5) + wb]; \
    _Pragma("unroll") \
    for (int j = 0; j < 4; ++j) \
      bf[j] = *(const bf16x8*)&ldsB[S_][((brow0 + j * 16) << 5) + wb]; \
    if (PF_) { STAGE_A((kt_) + 3, ((S_) + 3) & 3); STAGE_B((kt_) + 3, ((S_) + 3) & 3); } \
    __builtin_amdgcn_s_setprio(1); \
    _Pragma("unroll") \
    for (int i = 0; i < 8; ++i) \
      _Pragma("unroll") \
      for (int j = 0; j < 4; ++j) \
        acc[i][j] = __builtin_amdgcn_mfma_f32_16x16x32_bf16(af[i], bf[j], acc[i][j], 0, 0, 0); \
    __builtin_amdgcn_s_setprio(0); \
    if ((VMC_) == 8)      { asm volatile("s_waitcnt vmcnt(8)" ::: "memory"); } \
    else if ((VMC_) == 4) { asm volatile("s_waitcnt vmcnt(4)" ::: "memory"); } \
    else if ((VMC_) == 0) { asm volatile("s_waitcnt vmcnt(0)" ::: "memory"); } \
    if (TAILBAR_) SBAR(); \
  } while (0)

  STAGE_A(0, 0); STAGE_B(0, 0);
  STAGE_A(1, 1); STAGE_B(1, 1);
  STAGE_A(2, 2); STAGE_B(2, 2);
  asm volatile("s_waitcnt vmcnt(8)" ::: "memory");
  SBAR();

  const int ng = nt >> 2;
  for (int g = 0; g < ng - 1; ++g) {
    const int kt0 = g << 2;
    KSTEP(kt0 + 0, 0, true, 8, true);
    KSTEP(kt0 + 1, 1, true, 8, true);
    KSTEP(kt0 + 2, 2, true, 8, true);
    KSTEP(kt0 + 3, 3, true, 8, true);
  }
  {
    const int kt0 = nt - 4;
    KSTEP(kt0 + 0, 0, true, 8, true);
    KSTEP(kt0 + 1, 1, false, 4, true);
    KSTEP(kt0 + 2, 2, false, 0, true);
    KSTEP(kt0 + 3, 3, false, -1, false);
  }
#undef KSTEP
#undef STAGE_A
#undef STAGE_B

#pragma unroll
  for (int i = 0; i < 8; ++i)
#pragma unroll
    for (int j = 0; j < 4; ++j) {
      int row = bm * 256 + wm * 128 + i * 16 + lk * 4;
      int col = bn * 256 + wn * 64 + j * 16 + lr;
#pragma unroll
      for (int r = 0; r < 4; ++r) {
        if constexpr (F32OUT)
          ((float*)Cm)[(size_t)(row + r) * N + col] = acc[i][j][r];
        else
          ((unsigned short*)Cm)[(size_t)(row + r) * N + col] = f2bf(acc[i][j][r]);
      }
    }
}

// ---------------- 128x256 bf16 GEMM, 2 blocks/CU (fill variant for out-proj) ----------------
// r17: same r10 skeleton (ring-4, 1 barrier/step, counted vmcnt, setprio, same
// 0-conflict swizzle) at BM=128 so grid = 32 x 10 = 320 blocks co-resident at
// 2 blocks/CU (LDS 64KB, VGPR ~80). Fixes out-proj's 62% fill (160/256 CUs).
// Per step: 3 loads/thread (A 1, B 2); after stage, 9 outstanding -> tail
// vmcnt(6) leaves tiles t+2,t+3 in flight. Drain: 6/3/0/none.
// B row 128 offset keeps the XOR term: (128+r)>>1 & 3 == (r>>1)&3 (128%8==0).
template <bool F32OUT>
__global__ __launch_bounds__(512, 4) void k_gemm128(const unsigned short* __restrict__ A,
                                                    const unsigned short* __restrict__ Bt,
                                                    void* __restrict__ Cm,
                                                    int M, int N, int K) {
  __shared__ __align__(16) unsigned short ldsA[4][4096];  // [128][32] per slot
  __shared__ __align__(16) unsigned short ldsB[4][8192];  // [256][32] per slot
  const int nbn = N >> 8;
  int bid = blockIdx.x;
  int nwg = gridDim.x;
  if ((nwg & 7) == 0) {
    int cpx = nwg >> 3;
    bid = (bid & 7) * cpx + (bid >> 3);
  }
  const int bm = bid / nbn, bn = bid % nbn;
  const int tid = threadIdx.x;
  const int w = tid >> 6, l = tid & 63;
  const int wm = w >> 2, wn = w & 3;       // 2M x 4N, wave out = 64 x 64
  const int lr = l & 15, lk = l >> 4;
  const int nt = K >> 5;                   // nt % 4 == 0, nt >= 8

  const int rL = tid >> 2;
  const int swc = ((tid & 3) ^ ((tid >> 3) & 3)) << 3;
  const unsigned short* Ag = A + (size_t)(bm * 128 + rL) * K + swc;
  const unsigned short* Bg = Bt + (size_t)(bn * 256 + rL) * K + swc;
  const int wb = ((lk ^ ((lr >> 1) & 3)) << 3);
  const int arow0 = wm * 64 + lr;
  const int brow0 = wn * 64 + lr;

  f32x4 acc[4][4] = {};

#define STAGE_A(kt_, s_) do { \
    gload16(Ag + (size_t)(kt_) * 32, (char*)&ldsA[s_][tid * 8]); } while (0)
#define STAGE_B(kt_, s_) do { \
    gload16(Bg + (size_t)(kt_) * 32,                    (char*)&ldsB[s_][tid * 8]); \
    gload16(Bg + (size_t)(kt_) * 32 + (size_t)128 * K,  (char*)&ldsB[s_][4096 + tid * 8]); } while (0)

#define KSTEP(kt_, S_, PF_, VMC_, TAILBAR_) do { \
    bf16x8 af[4], bf[4]; \
    _Pragma("unroll") \
    for (int i = 0; i < 4; ++i) \
      af[i] = *(const bf16x8*)&ldsA[S_][((arow0 + i * 16) << 5) + wb]; \
    _Pragma("unroll") \
    for (int j = 0; j < 4; ++j) \
      bf[j] = *(const bf16x8*)&ldsB[S_][((brow0 + j * 16) << 5) + wb]; \
    if (PF_) { STAGE_A((kt_) + 3, ((S_) + 3) & 3); STAGE_B((kt_) + 3, ((S_) + 3) & 3); } \
    __builtin_amdgcn_s_setprio(1); \
    _Pragma("unroll") \
    for (int i = 0; i < 4; ++i) \
      _Pragma("unroll") \
      for (int j = 0; j < 4; ++j) \
        acc[i][j] = __builtin_amdgcn_mfma_f32_16x16x32_bf16(af[i], bf[j], acc[i][j], 0, 0, 0); \
    __builtin_amdgcn_s_setprio(0); \
    if ((VMC_) == 6)      { asm volatile("s_waitcnt vmcnt(6)" ::: "memory"); } \
    else if ((VMC_) == 3) { asm volatile("s_waitcnt vmcnt(3)" ::: "memory"); } \
    else if ((VMC_) == 0) { asm volatile("s_waitcnt vmcnt(0)" ::: "memory"); } \
    if (TAILBAR_) SBAR(); \
  } while (0)

  STAGE_A(0, 0); STAGE_B(0, 0);
  STAGE_A(1, 1); STAGE_B(1, 1);
  STAGE_A(2, 2); STAGE_B(2, 2);
  asm volatile("s_waitcnt vmcnt(6)" ::: "memory");
  SBAR();

  const int ng = nt >> 2;
  for (int g = 0; g < ng - 1; ++g) {
    const int kt0 = g << 2;
    KSTEP(kt0 + 0, 0, true, 6, true);
    KSTEP(kt0 + 1, 1, true, 6, true);
    KSTEP(kt0 + 2, 2, true, 6, true);
    KSTEP(kt0 + 3, 3, true, 6, true);
  }
  {
    const int kt0 = nt - 4;
    KSTEP(kt0 + 0, 0, true, 6, true);
    KSTEP(kt0 + 1, 1, false, 3, true);
    KSTEP(kt0 + 2, 2, false, 0, true);
    KSTEP(kt0 + 3, 3, false, -1, false);
  }
#undef KSTEP
#undef STAGE_A
#undef STAGE_B

#pragma unroll
  for (int i = 0; i < 4; ++i)
#pragma unroll
    for (int j = 0; j < 4; ++j) {
      int row = bm * 128 + wm * 64 + i * 16 + lk * 4;
      int col = bn * 256 + wn * 64 + j * 16 + lr;
#pragma unroll
      for (int r = 0; r < 4; ++r) {
        if constexpr (F32OUT)
          ((float*)Cm)[(size_t)(row + r) * N + col] = acc[i][j][r];
        else
          ((unsigned short*)Cm)[(size_t)(row + r) * N + col] = f2bf(acc[i][j][r]);
      }
    }
}

// ---------------- fused RMSNorm + RoPE; one wave per (b,s,head) row ----------------
__global__ __launch_bounds__(256) void k_norm_rope(
    const unsigned short* __restrict__ qkv,
    const float* __restrict__ qw, const float* __restrict__ kw,
    const float* __restrict__ ct, const float* __restrict__ st,
    unsigned short* __restrict__ Qh, unsigned short* __restrict__ Kh) {
  int gwid = (blockIdx.x * 256 + threadIdx.x) >> 6;  // 0 .. 4096*12-1
  int l = threadIdx.x & 63;
  int head = gwid % 12;
  int bs = gwid / 12;
  int b = bs >> 11, s = bs & 2047;
  bool isq = head < 8;
  int col = isq ? head * 256 : 2048 + (head - 8) * 256;
  const unsigned short* src = qkv + (size_t)bs * 4096 + col;
  int d0 = l * 4;
  ushort4 u = *(const ushort4*)(src + d0);
  float x0 = bf2f(u.x), x1 = bf2f(u.y), x2 = bf2f(u.z), x3 = bf2f(u.w);
  float ss = x0 * x0 + x1 * x1 + x2 * x2 + x3 * x3;
#pragma unroll
  for (int off = 32; off > 0; off >>= 1) ss += __shfl_xor(ss, off);
  float inv = rsqrtf(ss * (1.0f / 256.0f) + 1e-6f);
  const float* wv = isq ? qw : kw;
  float4 w4 = *(const float4*)(wv + d0);
  float y0 = x0 * inv * (1.0f + w4.x);
  float y1 = x1 * inv * (1.0f + w4.y);
  float y2 = x2 * inv * (1.0f + w4.z);
  float y3 = x3 * inv * (1.0f + w4.w);
  int fb = (l & 31) * 4;
  float4 c4 = *(const float4*)(ct + s * 128 + fb);
  float4 s4 = *(const float4*)(st + s * 128 + fb);
  float p0 = __shfl_xor(y0, 32), p1 = __shfl_xor(y1, 32);
  float p2 = __shfl_xor(y2, 32), p3 = __shfl_xor(y3, 32);
  float sg = (l < 32) ? -1.0f : 1.0f;
  float o0 = y0 * c4.x + sg * p0 * s4.x;
  float o1 = y1 * c4.y + sg * p1 * s4.y;
  float o2 = y2 * c4.z + sg * p2 * s4.z;
  float o3 = y3 * c4.w + sg * p3 * s4.w;
  if (isq) {
    o0 *= QSCALE; o1 *= QSCALE; o2 *= QSCALE; o3 *= QSCALE;
    unsigned short* dst = Qh + (((size_t)(b * 8 + head)) * 2048 + s) * 256 + d0;
    ushort4 o; o.x = f2bf(o0); o.y = f2bf(o1); o.z = f2bf(o2); o.w = f2bf(o3);
    *(ushort4*)dst = o;
  } else {
    int hk = head - 8;
    int ch = d0 >> 3;
    int dsw = ((ch ^ (s & 7)) << 3) | (d0 & 7);
    unsigned short* dst = Kh + (((size_t)(b * 4 + hk)) * 2048 + s) * 256 + dsw;
    ushort4 o; o.x = f2bf(o0); o.y = f2bf(o1); o.z = f2bf(o2); o.w = f2bf(o3);
    *(ushort4*)dst = o;
  }
}

// ---------------- V transpose: qkv V slice -> VT[b][hkv][d][s^] bf16, swizzled ----------------
__global__ __launch_bounds__(256) void k_vtrans(const unsigned short* __restrict__ qkv,
                                                unsigned short* __restrict__ VT) {
  __shared__ __align__(16) unsigned short tile[64][72];  // 144B rows (16B aligned)
  int bid = blockIdx.x;  // [b][hk][stile(32)][dt(4)]
  int dt = bid & 3, stile = (bid >> 2) & 31, hk = (bid >> 7) & 3, b = bid >> 9;
  int s0 = stile * 64, d0 = dt * 64;
  int t = threadIdx.x;
#pragma unroll
  for (int i = 0; i < 2; i++) {
    int flat = i * 256 + t;
    int sl = flat >> 3, dc = flat & 7;
    ushort8 v = *(const ushort8*)&qkv[(size_t)(b * 2048 + s0 + sl) * 4096 + 3072 + hk * 256 + d0 + dc * 8];
    *(ushort8*)&tile[sl][dc * 8] = v;
  }
  __syncthreads();
#pragma unroll
  for (int i = 0; i < 2; i++) {
    int flat = i * 256 + t;
    int dl = flat >> 3, sc = flat & 7;
    ushort8 v;
#pragma unroll
    for (int j = 0; j < 8; j++) v[j] = tile[sc * 8 + j][dl];
    int dg = d0 + dl;
    int chg = (s0 >> 3) + sc;
    int swc = chg ^ (dg & 7);
    *(ushort8*)&VT[((size_t)(b * 4 + hk) * 256 + dg) * 2048 + swc * 8] = v;
  }
}

// ---------------- windowed flash attention, GQA-paired + double-buffered ----------------
// K/V tiles double-buffered in LDS; counted vmcnt(8) keeps next tile's loads in
// flight across barriers; raw SBAR (no __syncthreads -> no forced vmcnt(0)).
__global__ __launch_bounds__(512) void k_attn(
    const unsigned short* __restrict__ Qh,
    const unsigned short* __restrict__ Kh,
    const unsigned short* __restrict__ VT,
    const int* __restrict__ pos,
    unsigned short* __restrict__ Ao) {
  __shared__ __align__(16) unsigned short Ks[2][64 * 256];
  __shared__ __align__(16) unsigned short Vs[2][256 * 64];
  __shared__ __align__(16) unsigned short Ps[8][16 * 72];
  int bid = blockIdx.x;
  int qt = bid & 31, hk = (bid >> 5) & 3, b = bid >> 7;
  int t = threadIdx.x, w = t >> 6, l = t & 63;
  int lr = l & 15, lk = l >> 4;
  int h = hk * 2 + (w >> 2);
  int q0 = qt * 64, qrow0 = q0 + (w & 3) * 16;
  const unsigned short* qbase = Qh + (((size_t)(b * 8 + h)) * 2048 + (qrow0 + lr)) * 256;
  bf16x8 qf[8];
#pragma unroll
  for (int c = 0; c < 8; c++) qf[c] = *(const bf16x8*)&qbase[c * 32 + lk * 8];
  int pq[4];
#pragma unroll
  for (int r = 0; r < 4; r++) pq[r] = pos[qrow0 + lk * 4 + r];
  float m[4], ll[4];
  f32x4 oacc[16];
  f32x4 zero4 = {0.f, 0.f, 0.f, 0.f};
#pragma unroll
  for (int r = 0; r < 4; r++) { m[r] = -1e30f; ll[r] = 0.0f; }
#pragma unroll
  for (int nd = 0; nd < 16; nd++) oacc[nd] = zero4;
  const char* Kbase = (const char*)(Kh + ((size_t)(b * 4 + hk)) * 2048 * 256);
  const char* Vbase = (const char*)(VT + ((size_t)(b * 4 + hk)) * 256 * 2048);
  int jlo = q0 - 511; if (jlo < 0) jlo = 0; jlo &= ~63;
  const int ntj = ((q0 + 64) - jlo) >> 6;

#define ASTAGE(tj_) do { \
    const int j0_ = jlo + (tj_) * 64; \
    char* kd_ = (char*)Ks[(tj_) & 1]; \
    char* vd_ = (char*)Vs[(tj_) & 1]; \
    _Pragma("unroll") \
    for (int i = 0; i < 4; i++) \
      gload16(Kbase + (size_t)j0_ * 512 + i * 8192 + t * 16, kd_ + i * 8192 + w * 1024); \
    _Pragma("unroll") \
    for (int i = 0; i < 4; i++) { \
      int off_ = i * 8192 + t * 16; \
      int d_ = off_ >> 7, rb_ = off_ & 127; \
      gload16(Vbase + (size_t)d_ * 4096 + j0_ * 2 + rb_, vd_ + i * 8192 + w * 1024); \
    } \
  } while (0)

  ASTAGE(0);
  for (int tj = 0; tj < ntj; ++tj) {
    const int j0 = jlo + tj * 64;
    const char* Kb = (const char*)Ks[tj & 1];
    const char* Vb = (const char*)Vs[tj & 1];
    if (tj + 1 < ntj) {
      ASTAGE(tj + 1);
      asm volatile("s_waitcnt vmcnt(8)" ::: "memory");
    } else {
      asm volatile("s_waitcnt vmcnt(0)" ::: "memory");
    }
    SBAR();
    f32x4 sacc[4];
#pragma unroll
    for (int n = 0; n < 4; n++) sacc[n] = zero4;
    __builtin_amdgcn_s_setprio(1);
#pragma unroll
    for (int n = 0; n < 4; n++) {
      int key = n * 16 + lr;
      int sw = (key & 7) << 4;
#pragma unroll
      for (int c = 0; c < 8; c++) {
        bf16x8 kf = *(const bf16x8*)(Kb + key * 512 + ((c * 64 + lk * 16) ^ sw));
        sacc[n] = __builtin_amdgcn_mfma_f32_16x16x32_bf16(qf[c], kf, sacc[n], 0, 0, 0);
      }
    }
    __builtin_amdgcn_s_setprio(0);
    int pk[4];
#pragma unroll
    for (int n = 0; n < 4; n++) pk[n] = pos[j0 + n * 16 + lr];
#pragma unroll
    for (int n = 0; n < 4; n++)
#pragma unroll
      for (int r = 0; r < 4; r++) {
        int dq = pq[r] - pk[n];
        if (!(dq >= 0 && dq < 512)) sacc[n][r] = -1e30f;
      }
    float tm[4], rs[4], mn[4], corr[4];
#pragma unroll
    for (int r = 0; r < 4; r++)
      tm[r] = fmaxf(fmaxf(sacc[0][r], sacc[1][r]), fmaxf(sacc[2][r], sacc[3][r]));
#pragma unroll
    for (int d = 1; d < 16; d <<= 1)
#pragma unroll
      for (int r = 0; r < 4; r++) tm[r] = fmaxf(tm[r], __shfl_xor(tm[r], d));
#pragma unroll
    for (int r = 0; r < 4; r++) {
      mn[r] = fmaxf(m[r], tm[r]);
      corr[r] = exp2f(m[r] - mn[r]);
      rs[r] = 0.f;
    }
#pragma unroll
    for (int n = 0; n < 4; n++)
#pragma unroll
      for (int r = 0; r < 4; r++) {
        float sv = sacc[n][r];
        float p = (sv > -1e29f) ? exp2f(sv - mn[r]) : 0.0f;
        sacc[n][r] = p;
        rs[r] += p;
      }
#pragma unroll
    for (int d = 1; d < 16; d <<= 1)
#pragma unroll
      for (int r = 0; r < 4; r++) rs[r] += __shfl_xor(rs[r], d);
#pragma unroll
    for (int r = 0; r < 4; r++) { ll[r] = ll[r] * corr[r] + rs[r]; m[r] = mn[r]; }
#pragma unroll
    for (int nd = 0; nd < 16; nd++)
#pragma unroll
      for (int r = 0; r < 4; r++) oacc[nd][r] *= corr[r];
#pragma unroll
    for (int n = 0; n < 4; n++)
#pragma unroll
      for (int r = 0; r < 4; r++)
        Ps[w][(lk * 4 + r) * 72 + n * 16 + lr] = f2bf(sacc[n][r]);
#pragma unroll
    for (int c2 = 0; c2 < 2; c2++) {
      bf16x8 pf = *(const bf16x8*)&Ps[w][lr * 72 + c2 * 32 + lk * 8];
      __builtin_amdgcn_s_setprio(1);
#pragma unroll
      for (int nd = 0; nd < 16; nd++) {
        int dr = nd * 16 + lr;
        bf16x8 vf = *(const bf16x8*)(Vb + dr * 128 + ((c2 * 64 + lk * 16) ^ ((dr & 7) << 4)));
        oacc[nd] = __builtin_amdgcn_mfma_f32_16x16x32_bf16(pf, vf, oacc[nd], 0, 0, 0);
      }
      __builtin_amdgcn_s_setprio(0);
    }
    SBAR();
  }
#undef ASTAGE
#pragma unroll
  for (int r = 0; r < 4; r++) ll[r] = 1.0f / ll[r];
#pragma unroll
  for (int nd = 0; nd < 16; nd++)
#pragma unroll
    for (int r = 0; r < 4; r++) {
      float v = oacc[nd][r] * ll[r];
      Ao[((size_t)(b * 2048 + qrow0 + lk * 4 + r)) * 2048 + h * 256 + nd * 16 + lr] = f2bf(v);
    }
}

// ---------------- launch ----------------
// Workspace layout with lifetime-based reuse (peak ≈ 74 MB):
//   region0 [0, 33.55M):  QKV  -> later Ao [0,16.78M) + WoT [16.78M,27.26M)
//   region1 [33.55M, 54.53M): Xb -> later Qh
//   region2 [54.53M, 75.50M): WqT -> later Kh + VT
//   region3 [75.50M, 77.59M): ct, st
extern "C" void kernel_launch(void* const* d_in, const int* in_sizes, int n_in,
                              void* d_out, int out_size, void* d_ws, size_t ws_size,
                              hipStream_t stream) {
  const float* hs   = (const float*)d_in[0];
  const float* wqkv = (const float*)d_in[1];
  const float* wo   = (const float*)d_in[2];
  const float* qnw  = (const float*)d_in[3];
  const float* knw  = (const float*)d_in[4];
  const int*   pos  = (const int*)d_in[5];
  float* out = (float*)d_out;  // reference output dtype is float32

  char* base = (char*)d_ws;
  const size_t OFF_R0 = 0;
  const size_t OFF_R1 = 33554432;
  const size_t OFF_R2 = 54525952;
  const size_t OFF_R3 = 75497472;

  unsigned short* QKV = (unsigned short*)(base + OFF_R0);
  unsigned short* Ao  = (unsigned short*)(base + OFF_R0);
  unsigned short* WoT = (unsigned short*)(base + OFF_R0 + 16777216);
  unsigned short* Xb  = (unsigned short*)(base + OFF_R1);
  unsigned short* Qh  = (unsigned short*)(base + OFF_R1);
  unsigned short* WqT = (unsigned short*)(base + OFF_R2);
  unsigned short* Kh  = (unsigned short*)(base + OFF_R2);
  unsigned short* VT  = (unsigned short*)(base + OFF_R2 + 8388608);
  float* ct = (float*)(base + OFF_R3);
  float* st = (float*)(base + OFF_R3 + 1048576);

  k_rope_tab<<<1024, 256, 0, stream>>>(pos, ct, st);
  k_cvt_bf16<<<10240, 256, 0, stream>>>(hs, Xb, 2621440);
  k_transpose_w<<<dim3(128, 80), 256, 0, stream>>>(wqkv, WqT, 2560, 4096);
  k_gemm256<false><<<256, 512, 0, stream>>>(Xb, WqT, QKV, 4096, 4096, 2560);   // Xb, WqT dead after
  k_norm_rope<<<12288, 256, 0, stream>>>(QKV, qnw, knw, ct, st, Qh, Kh);       // Qh over Xb, Kh over WqT
  k_vtrans<<<1024, 256, 0, stream>>>(QKV, VT);                                 // QKV dead after
  k_transpose_w<<<dim3(80, 64), 256, 0, stream>>>(wo, WoT, 2048, 2560);        // WoT over QKV tail
  k_attn<<<256, 512, 0, stream>>>(Qh, Kh, VT, pos, Ao);                        // Ao over QKV head
  k_gemm128<true><<<320, 512, 0, stream>>>(Ao, WoT, out, 4096, 2560, 2048);    // fp32 out, 2 blocks/CU
}

// Round 18
// 246.966 us; speedup vs baseline: 1.0092x; 1.0092x over previous
//
#include <hip/hip_runtime.h>
#include <hip/hip_bf16.h>
#include <stdint.h>

// Problem constants
// B=2 S=2048 HID=2560 H=8 HKV=4 D=256 GROUPS=2 window=512
#define QSCALE 0.09016844005555459f  // (1/16) * log2(e)

typedef __attribute__((ext_vector_type(4))) float f32x4;
typedef __attribute__((ext_vector_type(8))) __bf16 bf16x8;
typedef __attribute__((ext_vector_type(8))) unsigned short ushort8;

static __device__ __forceinline__ float bf2f(unsigned short v) {
  union { unsigned u; float f; } x; x.u = ((unsigned)v) << 16; return x.f;
}
static __device__ __forceinline__ unsigned short f2bf(float f) {
  union { float f; unsigned u; } x; x.f = f;
  unsigned r = x.u + 0x7fffu + ((x.u >> 16) & 1u);
  return (unsigned short)(r >> 16);
}
static __device__ __forceinline__ void gload16(const void* g, void* l) {
  __builtin_amdgcn_global_load_lds((const __attribute__((address_space(1))) void*)g,
                                   (__attribute__((address_space(3))) void*)l, 16, 0, 0);
}
#define SBAR() __builtin_amdgcn_s_barrier()

// ---------------- rope table: ct/st[s][j], j=0..127 ----------------
__global__ __launch_bounds__(256) void k_rope_tab(const int* __restrict__ pos,
                                                  float* __restrict__ ct,
                                                  float* __restrict__ st) {
  int idx = blockIdx.x * 256 + threadIdx.x;  // S*128 = 262144 exact
  int s = idx >> 7, j = idx & 127;
  float inv = exp2f((float)j * (-13.287712379549449f / 128.0f));  // 10000^(-j/128)
  float ang = (float)pos[s] * inv;
  float sv, cv;
  sincosf(ang, &sv, &cv);
  ct[idx] = cv; st[idx] = sv;
}

// ---------------- fp32 -> bf16 elementwise (vectorized) ----------------
__global__ __launch_bounds__(256) void k_cvt_bf16(const float* __restrict__ in,
                                                  unsigned short* __restrict__ out, int n4) {
  int i = blockIdx.x * 256 + threadIdx.x;
  if (i >= n4) return;
  float4 v = ((const float4*)in)[i];
  ushort4 o; o.x = f2bf(v.x); o.y = f2bf(v.y); o.z = f2bf(v.z); o.w = f2bf(v.w);
  ((ushort4*)out)[i] = o;
}

// ---------------- transpose fp32 [R][C] -> bf16 [C][R] ----------------
__global__ __launch_bounds__(256) void k_transpose_w(const float* __restrict__ in,
                                                     unsigned short* __restrict__ out,
                                                     int R, int C) {
  __shared__ float tile[32][33];
  int c0 = blockIdx.x * 32, r0 = blockIdx.y * 32;
  int tx = threadIdx.x & 31, ty = threadIdx.x >> 5;  // 32 x 8
#pragma unroll
  for (int i = 0; i < 4; i++)
    tile[ty + 8*i][tx] = in[(size_t)(r0 + ty + 8*i) * C + c0 + tx];
  __syncthreads();
#pragma unroll
  for (int i = 0; i < 4; i++)
    out[(size_t)(c0 + ty + 8*i) * R + r0 + tx] = f2bf(tile[tx][ty + 8*i]);
}

// ---------------- 256x256 bf16 GEMM, BK=64 ring-2 (r18: barrier-thinning) ----------------
// Evidence: per-step time is INVARIANT across tile shape (91.6/80 = 73/64 =
// 1.14us/step) -> fixed per-step overhead dominates; barrier reduction is the
// only axis with consistent gains (r7->r8->r10). This halves barriers per K:
// one step = 64 K = {8 stage gloads issued FIRST} + 2 x {12 ds_reads + 32-MFMA
// cluster (setprio)} + vmcnt(0) + SBAR. The tail vmcnt(0) is free: stage was
// issued ~2500 MFMA-cycles earlier >> 900-cyc HBM latency.
// Ring-2 ledger: stage(t+1) -> buf 1-S; its readers were tile t-1's ds_reads,
// complete before t-1's tail SBAR (crossed entering t). RAW for tile t+1:
// this tile's tail vmcnt(0)+SBAR. LDS 128KB (2 buf x [A|B] x [256][64]).
// Slab layout per 32-K: identical to r10 ([128-row halves][32] linear, row<<5),
// kslab 1 at +8192 ushorts. Bank swizzle (verified 0-conflict): chunk ^=
// (row>>1)&3, inverse-swizzled GLOBAL source + swizzled ds_read (rule #21).
// Requires nt = K/64 even, >= 2.
template <bool F32OUT>
__global__ __launch_bounds__(512, 1) void k_gemm256(const unsigned short* __restrict__ A,
                                                    const unsigned short* __restrict__ Bt,
                                                    void* __restrict__ Cm,
                                                    int M, int N, int K) {
  __shared__ __align__(16) unsigned short ldsA[2][16384];  // [256][64] bf16 per buf
  __shared__ __align__(16) unsigned short ldsB[2][16384];
  const int nbn = N >> 8;
  int bid = blockIdx.x;
  int nwg = gridDim.x;
  if ((nwg & 7) == 0) {                    // XCD-aware swizzle (bijective: nwg%8==0)
    int cpx = nwg >> 3;
    bid = (bid & 7) * cpx + (bid >> 3);
  }
  const int bm = bid / nbn, bn = bid % nbn;
  const int tid = threadIdx.x;
  const int w = tid >> 6, l = tid & 63;
  const int wm = w >> 2, wn = w & 3;
  const int lr = l & 15, lk = l >> 4;
  const int nt = K >> 6;                   // BK = 64; nt even, >= 2

  const int rL = tid >> 2;
  const int swc = ((tid & 3) ^ ((tid >> 3) & 3)) << 3;
  const unsigned short* Ag = A + (size_t)(bm * 256 + rL) * K + swc;
  const unsigned short* Bg = Bt + (size_t)(bn * 256 + rL) * K + swc;
  const int ldsoff = w * 512;
  const int wb = ((lk ^ ((lr >> 1) & 3)) << 3);
  const int arow0 = wm * 128 + lr;
  const int brow0 = wn * 64 + lr;

  f32x4 acc[8][4] = {};

  // stage full 64-K tile kt into buffer s_ (8 gloads: 2 kslabs x 2 row-halves x A,B)
#define STAGE64(kt_, s_) do { \
    const size_t kb_ = (size_t)(kt_) * 64; \
    gload16(Ag + kb_,                         (char*)&ldsA[s_][ldsoff]); \
    gload16(Ag + kb_ + (size_t)128 * K,       (char*)&ldsA[s_][4096 + ldsoff]); \
    gload16(Ag + kb_ + 32,                    (char*)&ldsA[s_][8192 + ldsoff]); \
    gload16(Ag + kb_ + 32 + (size_t)128 * K,  (char*)&ldsA[s_][12288 + ldsoff]); \
    gload16(Bg + kb_,                         (char*)&ldsB[s_][ldsoff]); \
    gload16(Bg + kb_ + (size_t)128 * K,       (char*)&ldsB[s_][4096 + ldsoff]); \
    gload16(Bg + kb_ + 32,                    (char*)&ldsB[s_][8192 + ldsoff]); \
    gload16(Bg + kb_ + 32 + (size_t)128 * K,  (char*)&ldsB[s_][12288 + ldsoff]); \
  } while (0)

  // one 32-K sub-cluster from kslab KH of buffer S: 12 ds_reads + 32 MFMA
#define HALF64(S_, KH_) do { \
    bf16x8 af[8], bf[4]; \
    _Pragma("unroll") \
    for (int i = 0; i < 8; ++i) \
      af[i] = *(const bf16x8*)&ldsA[S_][(KH_) * 8192 + ((arow0 + i * 16) << 5) + wb]; \
    _Pragma("unroll") \
    for (int j = 0; j < 4; ++j) \
      bf[j] = *(const bf16x8*)&ldsB[S_][(KH_) * 8192 + ((brow0 + j * 16) << 5) + wb]; \
    __builtin_amdgcn_s_setprio(1); \
    _Pragma("unroll") \
    for (int i = 0; i < 8; ++i) \
      _Pragma("unroll") \
      for (int j = 0; j < 4; ++j) \
        acc[i][j] = __builtin_amdgcn_mfma_f32_16x16x32_bf16(af[i], bf[j], acc[i][j], 0, 0, 0); \
    __builtin_amdgcn_s_setprio(0); \
  } while (0)

#define TILE64(kt_, S_, PF_) do { \
    if (PF_) STAGE64((kt_) + 1, 1 - (S_)); \
    HALF64(S_, 0); \
    HALF64(S_, 1); \
    if (PF_) { asm volatile("s_waitcnt vmcnt(0)" ::: "memory"); SBAR(); } \
  } while (0)

  // prologue: stage tile 0
  STAGE64(0, 0);
  asm volatile("s_waitcnt vmcnt(0)" ::: "memory");
  SBAR();

  for (int kt = 0; kt < nt; kt += 2) {
    TILE64(kt, 0, true);                   // kt+1 < nt always (nt even)
    TILE64(kt + 1, 1, (kt + 2) < nt);
  }
#undef TILE64
#undef HALF64
#undef STAGE64

#pragma unroll
  for (int i = 0; i < 8; ++i)
#pragma unroll
    for (int j = 0; j < 4; ++j) {
      int row = bm * 256 + wm * 128 + i * 16 + lk * 4;
      int col = bn * 256 + wn * 64 + j * 16 + lr;
#pragma unroll
      for (int r = 0; r < 4; ++r) {
        if constexpr (F32OUT)
          ((float*)Cm)[(size_t)(row + r) * N + col] = acc[i][j][r];
        else
          ((unsigned short*)Cm)[(size_t)(row + r) * N + col] = f2bf(acc[i][j][r]);
      }
    }
}

// ---------------- fused RMSNorm + RoPE; one wave per (b,s,head) row ----------------
__global__ __launch_bounds__(256) void k_norm_rope(
    const unsigned short* __restrict__ qkv,
    const float* __restrict__ qw, const float* __restrict__ kw,
    const float* __restrict__ ct, const float* __restrict__ st,
    unsigned short* __restrict__ Qh, unsigned short* __restrict__ Kh) {
  int gwid = (blockIdx.x * 256 + threadIdx.x) >> 6;  // 0 .. 4096*12-1
  int l = threadIdx.x & 63;
  int head = gwid % 12;
  int bs = gwid / 12;
  int b = bs >> 11, s = bs & 2047;
  bool isq = head < 8;
  int col = isq ? head * 256 : 2048 + (head - 8) * 256;
  const unsigned short* src = qkv + (size_t)bs * 4096 + col;
  int d0 = l * 4;
  ushort4 u = *(const ushort4*)(src + d0);
  float x0 = bf2f(u.x), x1 = bf2f(u.y), x2 = bf2f(u.z), x3 = bf2f(u.w);
  float ss = x0 * x0 + x1 * x1 + x2 * x2 + x3 * x3;
#pragma unroll
  for (int off = 32; off > 0; off >>= 1) ss += __shfl_xor(ss, off);
  float inv = rsqrtf(ss * (1.0f / 256.0f) + 1e-6f);
  const float* wv = isq ? qw : kw;
  float4 w4 = *(const float4*)(wv + d0);
  float y0 = x0 * inv * (1.0f + w4.x);
  float y1 = x1 * inv * (1.0f + w4.y);
  float y2 = x2 * inv * (1.0f + w4.z);
  float y3 = x3 * inv * (1.0f + w4.w);
  int fb = (l & 31) * 4;
  float4 c4 = *(const float4*)(ct + s * 128 + fb);
  float4 s4 = *(const float4*)(st + s * 128 + fb);
  float p0 = __shfl_xor(y0, 32), p1 = __shfl_xor(y1, 32);
  float p2 = __shfl_xor(y2, 32), p3 = __shfl_xor(y3, 32);
  float sg = (l < 32) ? -1.0f : 1.0f;
  float o0 = y0 * c4.x + sg * p0 * s4.x;
  float o1 = y1 * c4.y + sg * p1 * s4.y;
  float o2 = y2 * c4.z + sg * p2 * s4.z;
  float o3 = y3 * c4.w + sg * p3 * s4.w;
  if (isq) {
    o0 *= QSCALE; o1 *= QSCALE; o2 *= QSCALE; o3 *= QSCALE;
    unsigned short* dst = Qh + (((size_t)(b * 8 + head)) * 2048 + s) * 256 + d0;
    ushort4 o; o.x = f2bf(o0); o.y = f2bf(o1); o.z = f2bf(o2); o.w = f2bf(o3);
    *(ushort4*)dst = o;
  } else {
    int hk = head - 8;
    int ch = d0 >> 3;
    int dsw = ((ch ^ (s & 7)) << 3) | (d0 & 7);
    unsigned short* dst = Kh + (((size_t)(b * 4 + hk)) * 2048 + s) * 256 + dsw;
    ushort4 o; o.x = f2bf(o0); o.y = f2bf(o1); o.z = f2bf(o2); o.w = f2bf(o3);
    *(ushort4*)dst = o;
  }
}

// ---------------- V transpose: qkv V slice -> VT[b][hkv][d][s^] bf16, swizzled ----------------
__global__ __launch_bounds__(256) void k_vtrans(const unsigned short* __restrict__ qkv,
                                                unsigned short* __restrict__ VT) {
  __shared__ __align__(16) unsigned short tile[64][72];  // 144B rows (16B aligned)
  int bid = blockIdx.x;  // [b][hk][stile(32)][dt(4)]
  int dt = bid & 3, stile = (bid >> 2) & 31, hk = (bid >> 7) & 3, b = bid >> 9;
  int s0 = stile * 64, d0 = dt * 64;
  int t = threadIdx.x;
#pragma unroll
  for (int i = 0; i < 2; i++) {
    int flat = i * 256 + t;
    int sl = flat >> 3, dc = flat & 7;
    ushort8 v = *(const ushort8*)&qkv[(size_t)(b * 2048 + s0 + sl) * 4096 + 3072 + hk * 256 + d0 + dc * 8];
    *(ushort8*)&tile[sl][dc * 8] = v;
  }
  __syncthreads();
#pragma unroll
  for (int i = 0; i < 2; i++) {
    int flat = i * 256 + t;
    int dl = flat >> 3, sc = flat & 7;
    ushort8 v;
#pragma unroll
    for (int j = 0; j < 8; j++) v[j] = tile[sc * 8 + j][dl];
    int dg = d0 + dl;
    int chg = (s0 >> 3) + sc;
    int swc = chg ^ (dg & 7);
    *(ushort8*)&VT[((size_t)(b * 4 + hk) * 256 + dg) * 2048 + swc * 8] = v;
  }
}

// ---------------- windowed flash attention, GQA-paired + double-buffered ----------------
__global__ __launch_bounds__(512) void k_attn(
    const unsigned short* __restrict__ Qh,
    const unsigned short* __restrict__ Kh,
    const unsigned short* __restrict__ VT,
    const int* __restrict__ pos,
    unsigned short* __restrict__ Ao) {
  __shared__ __align__(16) unsigned short Ks[2][64 * 256];
  __shared__ __align__(16) unsigned short Vs[2][256 * 64];
  __shared__ __align__(16) unsigned short Ps[8][16 * 72];
  int bid = blockIdx.x;
  int qt = bid & 31, hk = (bid >> 5) & 3, b = bid >> 7;
  int t = threadIdx.x, w = t >> 6, l = t & 63;
  int lr = l & 15, lk = l >> 4;
  int h = hk * 2 + (w >> 2);
  int q0 = qt * 64, qrow0 = q0 + (w & 3) * 16;
  const unsigned short* qbase = Qh + (((size_t)(b * 8 + h)) * 2048 + (qrow0 + lr)) * 256;
  bf16x8 qf[8];
#pragma unroll
  for (int c = 0; c < 8; c++) qf[c] = *(const bf16x8*)&qbase[c * 32 + lk * 8];
  int pq[4];
#pragma unroll
  for (int r = 0; r < 4; r++) pq[r] = pos[qrow0 + lk * 4 + r];
  float m[4], ll[4];
  f32x4 oacc[16];
  f32x4 zero4 = {0.f, 0.f, 0.f, 0.f};
#pragma unroll
  for (int r = 0; r < 4; r++) { m[r] = -1e30f; ll[r] = 0.0f; }
#pragma unroll
  for (int nd = 0; nd < 16; nd++) oacc[nd] = zero4;
  const char* Kbase = (const char*)(Kh + ((size_t)(b * 4 + hk)) * 2048 * 256);
  const char* Vbase = (const char*)(VT + ((size_t)(b * 4 + hk)) * 256 * 2048);
  int jlo = q0 - 511; if (jlo < 0) jlo = 0; jlo &= ~63;
  const int ntj = ((q0 + 64) - jlo) >> 6;

#define ASTAGE(tj_) do { \
    const int j0_ = jlo + (tj_) * 64; \
    char* kd_ = (char*)Ks[(tj_) & 1]; \
    char* vd_ = (char*)Vs[(tj_) & 1]; \
    _Pragma("unroll") \
    for (int i = 0; i < 4; i++) \
      gload16(Kbase + (size_t)j0_ * 512 + i * 8192 + t * 16, kd_ + i * 8192 + w * 1024); \
    _Pragma("unroll") \
    for (int i = 0; i < 4; i++) { \
      int off_ = i * 8192 + t * 16; \
      int d_ = off_ >> 7, rb_ = off_ & 127; \
      gload16(Vbase + (size_t)d_ * 4096 + j0_ * 2 + rb_, vd_ + i * 8192 + w * 1024); \
    } \
  } while (0)

  ASTAGE(0);
  for (int tj = 0; tj < ntj; ++tj) {
    const int j0 = jlo + tj * 64;
    const char* Kb = (const char*)Ks[tj & 1];
    const char* Vb = (const char*)Vs[tj & 1];
    if (tj + 1 < ntj) {
      ASTAGE(tj + 1);
      asm volatile("s_waitcnt vmcnt(8)" ::: "memory");
    } else {
      asm volatile("s_waitcnt vmcnt(0)" ::: "memory");
    }
    SBAR();
    f32x4 sacc[4];
#pragma unroll
    for (int n = 0; n < 4; n++) sacc[n] = zero4;
    __builtin_amdgcn_s_setprio(1);
#pragma unroll
    for (int n = 0; n < 4; n++) {
      int key = n * 16 + lr;
      int sw = (key & 7) << 4;
#pragma unroll
      for (int c = 0; c < 8; c++) {
        bf16x8 kf = *(const bf16x8*)(Kb + key * 512 + ((c * 64 + lk * 16) ^ sw));
        sacc[n] = __builtin_amdgcn_mfma_f32_16x16x32_bf16(qf[c], kf, sacc[n], 0, 0, 0);
      }
    }
    __builtin_amdgcn_s_setprio(0);
    int pk[4];
#pragma unroll
    for (int n = 0; n < 4; n++) pk[n] = pos[j0 + n * 16 + lr];
#pragma unroll
    for (int n = 0; n < 4; n++)
#pragma unroll
      for (int r = 0; r < 4; r++) {
        int dq = pq[r] - pk[n];
        if (!(dq >= 0 && dq < 512)) sacc[n][r] = -1e30f;
      }
    float tm[4], rs[4], mn[4], corr[4];
#pragma unroll
    for (int r = 0; r < 4; r++)
      tm[r] = fmaxf(fmaxf(sacc[0][r], sacc[1][r]), fmaxf(sacc[2][r], sacc[3][r]));
#pragma unroll
    for (int d = 1; d < 16; d <<= 1)
#pragma unroll
      for (int r = 0; r < 4; r++) tm[r] = fmaxf(tm[r], __shfl_xor(tm[r], d));
#pragma unroll
    for (int r = 0; r < 4; r++) {
      mn[r] = fmaxf(m[r], tm[r]);
      corr[r] = exp2f(m[r] - mn[r]);
      rs[r] = 0.f;
    }
#pragma unroll
    for (int n = 0; n < 4; n++)
#pragma unroll
      for (int r = 0; r < 4; r++) {
        float sv = sacc[n][r];
        float p = (sv > -1e29f) ? exp2f(sv - mn[r]) : 0.0f;
        sacc[n][r] = p;
        rs[r] += p;
      }
#pragma unroll
    for (int d = 1; d < 16; d <<= 1)
#pragma unroll
      for (int r = 0; r < 4; r++) rs[r] += __shfl_xor(rs[r], d);
#pragma unroll
    for (int r = 0; r < 4; r++) { ll[r] = ll[r] * corr[r] + rs[r]; m[r] = mn[r]; }
#pragma unroll
    for (int nd = 0; nd < 16; nd++)
#pragma unroll
      for (int r = 0; r < 4; r++) oacc[nd][r] *= corr[r];
#pragma unroll
    for (int n = 0; n < 4; n++)
#pragma unroll
      for (int r = 0; r < 4; r++)
        Ps[w][(lk * 4 + r) * 72 + n * 16 + lr] = f2bf(sacc[n][r]);
#pragma unroll
    for (int c2 = 0; c2 < 2; c2++) {
      bf16x8 pf = *(const bf16x8*)&Ps[w][lr * 72 + c2 * 32 + lk * 8];
      __builtin_amdgcn_s_setprio(1);
#pragma unroll
      for (int nd = 0; nd < 16; nd++) {
        int dr = nd * 16 + lr;
        bf16x8 vf = *(const bf16x8*)(Vb + dr * 128 + ((c2 * 64 + lk * 16) ^ ((dr & 7) << 4)));
        oacc[nd] = __builtin_amdgcn_mfma_f32_16x16x32_bf16(pf, vf, oacc[nd], 0, 0, 0);
      }
      __builtin_amdgcn_s_setprio(0);
    }
    SBAR();
  }
#undef ASTAGE
#pragma unroll
  for (int r = 0; r < 4; r++) ll[r] = 1.0f / ll[r];
#pragma unroll
  for (int nd = 0; nd < 16; nd++)
#pragma unroll
    for (int r = 0; r < 4; r++) {
      float v = oacc[nd][r] * ll[r];
      Ao[((size_t)(b * 2048 + qrow0 + lk * 4 + r)) * 2048 + h * 256 + nd * 16 + lr] = f2bf(v);
    }
}

// ---------------- launch ----------------
// Workspace layout with lifetime-based reuse (peak ≈ 74 MB):
//   region0 [0, 33.55M):  QKV  -> later Ao [0,16.78M) + WoT [16.78M,27.26M)
//   region1 [33.55M, 54.53M): Xb -> later Qh
//   region2 [54.53M, 75.50M): WqT -> later Kh + VT
//   region3 [75.50M, 77.59M): ct, st
extern "C" void kernel_launch(void* const* d_in, const int* in_sizes, int n_in,
                              void* d_out, int out_size, void* d_ws, size_t ws_size,
                              hipStream_t stream) {
  const float* hs   = (const float*)d_in[0];
  const float* wqkv = (const float*)d_in[1];
  const float* wo   = (const float*)d_in[2];
  const float* qnw  = (const float*)d_in[3];
  const float* knw  = (const float*)d_in[4];
  const int*   pos  = (const int*)d_in[5];
  float* out = (float*)d_out;  // reference output dtype is float32

  char* base = (char*)d_ws;
  const size_t OFF_R0 = 0;
  const size_t OFF_R1 = 33554432;
  const size_t OFF_R2 = 54525952;
  const size_t OFF_R3 = 75497472;

  unsigned short* QKV = (unsigned short*)(base + OFF_R0);
  unsigned short* Ao  = (unsigned short*)(base + OFF_R0);
  unsigned short* WoT = (unsigned short*)(base + OFF_R0 + 16777216);
  unsigned short* Xb  = (unsigned short*)(base + OFF_R1);
  unsigned short* Qh  = (unsigned short*)(base + OFF_R1);
  unsigned short* WqT = (unsigned short*)(base + OFF_R2);
  unsigned short* Kh  = (unsigned short*)(base + OFF_R2);
  unsigned short* VT  = (unsigned short*)(base + OFF_R2 + 8388608);
  float* ct = (float*)(base + OFF_R3);
  float* st = (float*)(base + OFF_R3 + 1048576);

  k_rope_tab<<<1024, 256, 0, stream>>>(pos, ct, st);
  k_cvt_bf16<<<10240, 256, 0, stream>>>(hs, Xb, 2621440);
  k_transpose_w<<<dim3(128, 80), 256, 0, stream>>>(wqkv, WqT, 2560, 4096);
  k_gemm256<false><<<256, 512, 0, stream>>>(Xb, WqT, QKV, 4096, 4096, 2560);   // Xb, WqT dead after
  k_norm_rope<<<12288, 256, 0, stream>>>(QKV, qnw, knw, ct, st, Qh, Kh);       // Qh over Xb, Kh over WqT
  k_vtrans<<<1024, 256, 0, stream>>>(QKV, VT);                                 // QKV dead after
  k_transpose_w<<<dim3(80, 64), 256, 0, stream>>>(wo, WoT, 2048, 2560);        // WoT over QKV tail
  k_attn<<<256, 512, 0, stream>>>(Qh, Kh, VT, pos, Ao);                        // Ao over QKV head
  k_gemm256<true><<<160, 512, 0, stream>>>(Ao, WoT, out, 4096, 2560, 2048);    // fp32 out
}

// Round 19
// 227.719 us; speedup vs baseline: 1.0945x; 1.0845x over previous
//
#include <hip/hip_runtime.h>
#include <hip/hip_bf16.h>
#include <stdint.h>

// Problem constants
// B=2 S=2048 HID=2560 H=8 HKV=4 D=256 GROUPS=2 window=512
#define QSCALE 0.09016844005555459f  // (1/16) * log2(e)

typedef __attribute__((ext_vector_type(4))) float f32x4;
typedef __attribute__((ext_vector_type(8))) __bf16 bf16x8;
typedef __attribute__((ext_vector_type(8))) unsigned short ushort8;

static __device__ __forceinline__ float bf2f(unsigned short v) {
  union { unsigned u; float f; } x; x.u = ((unsigned)v) << 16; return x.f;
}
static __device__ __forceinline__ unsigned short f2bf(float f) {
  union { float f; unsigned u; } x; x.f = f;
  unsigned r = x.u + 0x7fffu + ((x.u >> 16) & 1u);
  return (unsigned short)(r >> 16);
}
static __device__ __forceinline__ void gload16(const void* g, void* l) {
  __builtin_amdgcn_global_load_lds((const __attribute__((address_space(1))) void*)g,
                                   (__attribute__((address_space(3))) void*)l, 16, 0, 0);
}
#define SBAR() __builtin_amdgcn_s_barrier()

// ---------------- fp32 -> bf16 elementwise + fused rope table ----------------
// r19: rope-table generation folded into the cvt kernel (blocks 0..1023 also
// compute ct/st[s][j]) — one fewer launch; both are memory-bound prep.
__global__ __launch_bounds__(256) void k_cvt_bf16(const float* __restrict__ in,
                                                  unsigned short* __restrict__ out, int n4,
                                                  const int* __restrict__ pos,
                                                  float* __restrict__ ct,
                                                  float* __restrict__ st) {
  int i = blockIdx.x * 256 + threadIdx.x;
  if (blockIdx.x < 1024) {                  // rope table: S*128 = 262144 entries
    int idx = i;
    int s = idx >> 7, j = idx & 127;
    float inv = exp2f((float)j * (-13.287712379549449f / 128.0f));  // 10000^(-j/128)
    float ang = (float)pos[s] * inv;
    float sv, cv;
    sincosf(ang, &sv, &cv);
    ct[idx] = cv; st[idx] = sv;
  }
  if (i >= n4) return;
  float4 v = ((const float4*)in)[i];
  ushort4 o; o.x = f2bf(v.x); o.y = f2bf(v.y); o.z = f2bf(v.z); o.w = f2bf(v.w);
  ((ushort4*)out)[i] = o;
}

// ---------------- transpose fp32 [R][C] -> bf16 [C][R] ----------------
__global__ __launch_bounds__(256) void k_transpose_w(const float* __restrict__ in,
                                                     unsigned short* __restrict__ out,
                                                     int R, int C) {
  __shared__ float tile[32][33];
  int c0 = blockIdx.x * 32, r0 = blockIdx.y * 32;
  int tx = threadIdx.x & 31, ty = threadIdx.x >> 5;  // 32 x 8
#pragma unroll
  for (int i = 0; i < 4; i++)
    tile[ty + 8*i][tx] = in[(size_t)(r0 + ty + 8*i) * C + c0 + tx];
  __syncthreads();
#pragma unroll
  for (int i = 0; i < 4; i++)
    out[(size_t)(c0 + ty + 8*i) * R + r0 + tx] = f2bf(tile[tx][ty + 8*i]);
}

// ---------------- 256x256 bf16 GEMM (r10 structure — best measured, FINAL) ----------------
// BK=32, ring of 4 LDS slots (128KB), 8 waves (2Mx4N), counted vmcnt(8) (never
// 0 mid-loop), ONE raw s_barrier per K-step, setprio around the 32-MFMA cluster.
// Ledger: RAW: entering step kt, tile kt in LDS for ALL waves (tail of kt-1 did
// vmcnt(8) + SBAR). WAR: stage(kt+3) -> slot (kt-1)&3; readers were step kt-1's
// ds_reads, complete before its MFMA (lgkm) which precedes the tail SBAR.
// Bank swizzle (verified 0-conflict): chunk ^= (row>>1)&3, inverse-swizzled
// GLOBAL source + swizzled ds_read (rule #21). Requires nt % 4 == 0, nt >= 8.
template <bool F32OUT>
__global__ __launch_bounds__(512, 1) void k_gemm256(const unsigned short* __restrict__ A,
                                                    const unsigned short* __restrict__ Bt,
                                                    void* __restrict__ Cm,
                                                    int M, int N, int K) {
  __shared__ __align__(16) unsigned short ldsA[4][8192];  // 4 slots x [256][32] bf16 (swizzled)
  __shared__ __align__(16) unsigned short ldsB[4][8192];
  const int nbn = N >> 8;
  int bid = blockIdx.x;
  int nwg = gridDim.x;
  if ((nwg & 7) == 0) {                    // XCD-aware swizzle (bijective: nwg%8==0)
    int cpx = nwg >> 3;
    bid = (bid & 7) * cpx + (bid >> 3);
  }
  const int bm = bid / nbn, bn = bid % nbn;
  const int tid = threadIdx.x;
  const int w = tid >> 6, l = tid & 63;
  const int wm = w >> 2, wn = w & 3;
  const int lr = l & 15, lk = l >> 4;
  const int nt = K >> 5;                   // BK = 32; nt % 4 == 0, nt >= 8

  const int rL = tid >> 2;
  const int swc = ((tid & 3) ^ ((tid >> 3) & 3)) << 3;
  const unsigned short* Ag = A + (size_t)(bm * 256 + rL) * K + swc;
  const unsigned short* Bg = Bt + (size_t)(bn * 256 + rL) * K + swc;
  const int ldsoff = w * 512;
  const int wb = ((lk ^ ((lr >> 1) & 3)) << 3);
  const int arow0 = wm * 128 + lr;
  const int brow0 = wn * 64 + lr;

  f32x4 acc[8][4] = {};

#define STAGE_A(kt_, s_) do { \
    gload16(Ag + (size_t)(kt_) * 32,                    (char*)&ldsA[s_][ldsoff]); \
    gload16(Ag + (size_t)(kt_) * 32 + (size_t)128 * K,  (char*)&ldsA[s_][4096 + ldsoff]); } while (0)
#define STAGE_B(kt_, s_) do { \
    gload16(Bg + (size_t)(kt_) * 32,                    (char*)&ldsB[s_][ldsoff]); \
    gload16(Bg + (size_t)(kt_) * 32 + (size_t)128 * K,  (char*)&ldsB[s_][4096 + ldsoff]); } while (0)

#define KSTEP(kt_, S_, PF_, VMC_, TAILBAR_) do { \
    bf16x8 af[8], bf[4]; \
    _Pragma("unroll") \
    for (int i = 0; i < 8; ++i) \
      af[i] = *(const bf16x8*)&ldsA[S_][((arow0 + i * 16) << 5) + wb]; \
    _Pragma("unroll") \
    for (int j = 0; j < 4; ++j) \
      bf[j] = *(const bf16x8*)&ldsB[S_][((brow0 + j * 16) << 5) + wb]; \
    if (PF_) { STAGE_A((kt_) + 3, ((S_) + 3) & 3); STAGE_B((kt_) + 3, ((S_) + 3) & 3); } \
    __builtin_amdgcn_s_setprio(1); \
    _Pragma("unroll") \
    for (int i = 0; i < 8; ++i) \
      _Pragma("unroll") \
      for (int j = 0; j < 4; ++j) \
        acc[i][j] = __builtin_amdgcn_mfma_f32_16x16x32_bf16(af[i], bf[j], acc[i][j], 0, 0, 0); \
    __builtin_amdgcn_s_setprio(0); \
    if ((VMC_) == 8)      { asm volatile("s_waitcnt vmcnt(8)" ::: "memory"); } \
    else if ((VMC_) == 4) { asm volatile("s_waitcnt vmcnt(4)" ::: "memory"); } \
    else if ((VMC_) == 0) { asm volatile("s_waitcnt vmcnt(0)" ::: "memory"); } \
    if (TAILBAR_) SBAR(); \
  } while (0)

  STAGE_A(0, 0); STAGE_B(0, 0);
  STAGE_A(1, 1); STAGE_B(1, 1);
  STAGE_A(2, 2); STAGE_B(2, 2);
  asm volatile("s_waitcnt vmcnt(8)" ::: "memory");
  SBAR();

  const int ng = nt >> 2;
  for (int g = 0; g < ng - 1; ++g) {
    const int kt0 = g << 2;
    KSTEP(kt0 + 0, 0, true, 8, true);
    KSTEP(kt0 + 1, 1, true, 8, true);
    KSTEP(kt0 + 2, 2, true, 8, true);
    KSTEP(kt0 + 3, 3, true, 8, true);
  }
  {
    const int kt0 = nt - 4;
    KSTEP(kt0 + 0, 0, true, 8, true);
    KSTEP(kt0 + 1, 1, false, 4, true);
    KSTEP(kt0 + 2, 2, false, 0, true);
    KSTEP(kt0 + 3, 3, false, -1, false);
  }
#undef KSTEP
#undef STAGE_A
#undef STAGE_B

#pragma unroll
  for (int i = 0; i < 8; ++i)
#pragma unroll
    for (int j = 0; j < 4; ++j) {
      int row = bm * 256 + wm * 128 + i * 16 + lk * 4;
      int col = bn * 256 + wn * 64 + j * 16 + lr;
#pragma unroll
      for (int r = 0; r < 4; ++r) {
        if constexpr (F32OUT)
          ((float*)Cm)[(size_t)(row + r) * N + col] = acc[i][j][r];
        else
          ((unsigned short*)Cm)[(size_t)(row + r) * N + col] = f2bf(acc[i][j][r]);
      }
    }
}

// ---------------- fused RMSNorm + RoPE; one wave per (b,s,head) row ----------------
__global__ __launch_bounds__(256) void k_norm_rope(
    const unsigned short* __restrict__ qkv,
    const float* __restrict__ qw, const float* __restrict__ kw,
    const float* __restrict__ ct, const float* __restrict__ st,
    unsigned short* __restrict__ Qh, unsigned short* __restrict__ Kh) {
  int gwid = (blockIdx.x * 256 + threadIdx.x) >> 6;  // 0 .. 4096*12-1
  int l = threadIdx.x & 63;
  int head = gwid % 12;
  int bs = gwid / 12;
  int b = bs >> 11, s = bs & 2047;
  bool isq = head < 8;
  int col = isq ? head * 256 : 2048 + (head - 8) * 256;
  const unsigned short* src = qkv + (size_t)bs * 4096 + col;
  int d0 = l * 4;
  ushort4 u = *(const ushort4*)(src + d0);
  float x0 = bf2f(u.x), x1 = bf2f(u.y), x2 = bf2f(u.z), x3 = bf2f(u.w);
  float ss = x0 * x0 + x1 * x1 + x2 * x2 + x3 * x3;
#pragma unroll
  for (int off = 32; off > 0; off >>= 1) ss += __shfl_xor(ss, off);
  float inv = rsqrtf(ss * (1.0f / 256.0f) + 1e-6f);
  const float* wv = isq ? qw : kw;
  float4 w4 = *(const float4*)(wv + d0);
  float y0 = x0 * inv * (1.0f + w4.x);
  float y1 = x1 * inv * (1.0f + w4.y);
  float y2 = x2 * inv * (1.0f + w4.z);
  float y3 = x3 * inv * (1.0f + w4.w);
  int fb = (l & 31) * 4;
  float4 c4 = *(const float4*)(ct + s * 128 + fb);
  float4 s4 = *(const float4*)(st + s * 128 + fb);
  float p0 = __shfl_xor(y0, 32), p1 = __shfl_xor(y1, 32);
  float p2 = __shfl_xor(y2, 32), p3 = __shfl_xor(y3, 32);
  float sg = (l < 32) ? -1.0f : 1.0f;
  float o0 = y0 * c4.x + sg * p0 * s4.x;
  float o1 = y1 * c4.y + sg * p1 * s4.y;
  float o2 = y2 * c4.z + sg * p2 * s4.z;
  float o3 = y3 * c4.w + sg * p3 * s4.w;
  if (isq) {
    o0 *= QSCALE; o1 *= QSCALE; o2 *= QSCALE; o3 *= QSCALE;
    unsigned short* dst = Qh + (((size_t)(b * 8 + head)) * 2048 + s) * 256 + d0;
    ushort4 o; o.x = f2bf(o0); o.y = f2bf(o1); o.z = f2bf(o2); o.w = f2bf(o3);
    *(ushort4*)dst = o;
  } else {
    int hk = head - 8;
    int ch = d0 >> 3;
    int dsw = ((ch ^ (s & 7)) << 3) | (d0 & 7);
    unsigned short* dst = Kh + (((size_t)(b * 4 + hk)) * 2048 + s) * 256 + dsw;
    ushort4 o; o.x = f2bf(o0); o.y = f2bf(o1); o.z = f2bf(o2); o.w = f2bf(o3);
    *(ushort4*)dst = o;
  }
}

// ---------------- V transpose: qkv V slice -> VT[b][hkv][d][s^] bf16, swizzled ----------------
__global__ __launch_bounds__(256) void k_vtrans(const unsigned short* __restrict__ qkv,
                                                unsigned short* __restrict__ VT) {
  __shared__ __align__(16) unsigned short tile[64][72];  // 144B rows (16B aligned)
  int bid = blockIdx.x;  // [b][hk][stile(32)][dt(4)]
  int dt = bid & 3, stile = (bid >> 2) & 31, hk = (bid >> 7) & 3, b = bid >> 9;
  int s0 = stile * 64, d0 = dt * 64;
  int t = threadIdx.x;
#pragma unroll
  for (int i = 0; i < 2; i++) {
    int flat = i * 256 + t;
    int sl = flat >> 3, dc = flat & 7;
    ushort8 v = *(const ushort8*)&qkv[(size_t)(b * 2048 + s0 + sl) * 4096 + 3072 + hk * 256 + d0 + dc * 8];
    *(ushort8*)&tile[sl][dc * 8] = v;
  }
  __syncthreads();
#pragma unroll
  for (int i = 0; i < 2; i++) {
    int flat = i * 256 + t;
    int dl = flat >> 3, sc = flat & 7;
    ushort8 v;
#pragma unroll
    for (int j = 0; j < 8; j++) v[j] = tile[sc * 8 + j][dl];
    int dg = d0 + dl;
    int chg = (s0 >> 3) + sc;
    int swc = chg ^ (dg & 7);
    *(ushort8*)&VT[((size_t)(b * 4 + hk) * 256 + dg) * 2048 + swc * 8] = v;
  }
}

// ---------------- windowed flash attention, GQA-paired + double-buffered ----------------
// K/V tiles double-buffered in LDS; counted vmcnt(8) keeps next tile's loads in
// flight across barriers; raw SBAR (no __syncthreads -> no forced vmcnt(0)).
__global__ __launch_bounds__(512) void k_attn(
    const unsigned short* __restrict__ Qh,
    const unsigned short* __restrict__ Kh,
    const unsigned short* __restrict__ VT,
    const int* __restrict__ pos,
    unsigned short* __restrict__ Ao) {
  __shared__ __align__(16) unsigned short Ks[2][64 * 256];
  __shared__ __align__(16) unsigned short Vs[2][256 * 64];
  __shared__ __align__(16) unsigned short Ps[8][16 * 72];
  int bid = blockIdx.x;
  int qt = bid & 31, hk = (bid >> 5) & 3, b = bid >> 7;
  int t = threadIdx.x, w = t >> 6, l = t & 63;
  int lr = l & 15, lk = l >> 4;
  int h = hk * 2 + (w >> 2);
  int q0 = qt * 64, qrow0 = q0 + (w & 3) * 16;
  const unsigned short* qbase = Qh + (((size_t)(b * 8 + h)) * 2048 + (qrow0 + lr)) * 256;
  bf16x8 qf[8];
#pragma unroll
  for (int c = 0; c < 8; c++) qf[c] = *(const bf16x8*)&qbase[c * 32 + lk * 8];
  int pq[4];
#pragma unroll
  for (int r = 0; r < 4; r++) pq[r] = pos[qrow0 + lk * 4 + r];
  float m[4], ll[4];
  f32x4 oacc[16];
  f32x4 zero4 = {0.f, 0.f, 0.f, 0.f};
#pragma unroll
  for (int r = 0; r < 4; r++) { m[r] = -1e30f; ll[r] = 0.0f; }
#pragma unroll
  for (int nd = 0; nd < 16; nd++) oacc[nd] = zero4;
  const char* Kbase = (const char*)(Kh + ((size_t)(b * 4 + hk)) * 2048 * 256);
  const char* Vbase = (const char*)(VT + ((size_t)(b * 4 + hk)) * 256 * 2048);
  int jlo = q0 - 511; if (jlo < 0) jlo = 0; jlo &= ~63;
  const int ntj = ((q0 + 64) - jlo) >> 6;

#define ASTAGE(tj_) do { \
    const int j0_ = jlo + (tj_) * 64; \
    char* kd_ = (char*)Ks[(tj_) & 1]; \
    char* vd_ = (char*)Vs[(tj_) & 1]; \
    _Pragma("unroll") \
    for (int i = 0; i < 4; i++) \
      gload16(Kbase + (size_t)j0_ * 512 + i * 8192 + t * 16, kd_ + i * 8192 + w * 1024); \
    _Pragma("unroll") \
    for (int i = 0; i < 4; i++) { \
      int off_ = i * 8192 + t * 16; \
      int d_ = off_ >> 7, rb_ = off_ & 127; \
      gload16(Vbase + (size_t)d_ * 4096 + j0_ * 2 + rb_, vd_ + i * 8192 + w * 1024); \
    } \
  } while (0)

  ASTAGE(0);
  for (int tj = 0; tj < ntj; ++tj) {
    const int j0 = jlo + tj * 64;
    const char* Kb = (const char*)Ks[tj & 1];
    const char* Vb = (const char*)Vs[tj & 1];
    if (tj + 1 < ntj) {
      ASTAGE(tj + 1);
      asm volatile("s_waitcnt vmcnt(8)" ::: "memory");
    } else {
      asm volatile("s_waitcnt vmcnt(0)" ::: "memory");
    }
    SBAR();
    f32x4 sacc[4];
#pragma unroll
    for (int n = 0; n < 4; n++) sacc[n] = zero4;
    __builtin_amdgcn_s_setprio(1);
#pragma unroll
    for (int n = 0; n < 4; n++) {
      int key = n * 16 + lr;
      int sw = (key & 7) << 4;
#pragma unroll
      for (int c = 0; c < 8; c++) {
        bf16x8 kf = *(const bf16x8*)(Kb + key * 512 + ((c * 64 + lk * 16) ^ sw));
        sacc[n] = __builtin_amdgcn_mfma_f32_16x16x32_bf16(qf[c], kf, sacc[n], 0, 0, 0);
      }
    }
    __builtin_amdgcn_s_setprio(0);
    int pk[4];
#pragma unroll
    for (int n = 0; n < 4; n++) pk[n] = pos[j0 + n * 16 + lr];
#pragma unroll
    for (int n = 0; n < 4; n++)
#pragma unroll
      for (int r = 0; r < 4; r++) {
        int dq = pq[r] - pk[n];
        if (!(dq >= 0 && dq < 512)) sacc[n][r] = -1e30f;
      }
    float tm[4], rs[4], mn[4], corr[4];
#pragma unroll
    for (int r = 0; r < 4; r++)
      tm[r] = fmaxf(fmaxf(sacc[0][r], sacc[1][r]), fmaxf(sacc[2][r], sacc[3][r]));
#pragma unroll
    for (int d = 1; d < 16; d <<= 1)
#pragma unroll
      for (int r = 0; r < 4; r++) tm[r] = fmaxf(tm[r], __shfl_xor(tm[r], d));
#pragma unroll
    for (int r = 0; r < 4; r++) {
      mn[r] = fmaxf(m[r], tm[r]);
      corr[r] = exp2f(m[r] - mn[r]);
      rs[r] = 0.f;
    }
#pragma unroll
    for (int n = 0; n < 4; n++)
#pragma unroll
      for (int r = 0; r < 4; r++) {
        float sv = sacc[n][r];
        float p = (sv > -1e29f) ? exp2f(sv - mn[r]) : 0.0f;
        sacc[n][r] = p;
        rs[r] += p;
      }
#pragma unroll
    for (int d = 1; d < 16; d <<= 1)
#pragma unroll
      for (int r = 0; r < 4; r++) rs[r] += __shfl_xor(rs[r], d);
#pragma unroll
    for (int r = 0; r < 4; r++) { ll[r] = ll[r] * corr[r] + rs[r]; m[r] = mn[r]; }
#pragma unroll
    for (int nd = 0; nd < 16; nd++)
#pragma unroll
      for (int r = 0; r < 4; r++) oacc[nd][r] *= corr[r];
#pragma unroll
    for (int n = 0; n < 4; n++)
#pragma unroll
      for (int r = 0; r < 4; r++)
        Ps[w][(lk * 4 + r) * 72 + n * 16 + lr] = f2bf(sacc[n][r]);
#pragma unroll
    for (int c2 = 0; c2 < 2; c2++) {
      bf16x8 pf = *(const bf16x8*)&Ps[w][lr * 72 + c2 * 32 + lk * 8];
      __builtin_amdgcn_s_setprio(1);
#pragma unroll
      for (int nd = 0; nd < 16; nd++) {
        int dr = nd * 16 + lr;
        bf16x8 vf = *(const bf16x8*)(Vb + dr * 128 + ((c2 * 64 + lk * 16) ^ ((dr & 7) << 4)));
        oacc[nd] = __builtin_amdgcn_mfma_f32_16x16x32_bf16(pf, vf, oacc[nd], 0, 0, 0);
      }
      __builtin_amdgcn_s_setprio(0);
    }
    SBAR();
  }
#undef ASTAGE
#pragma unroll
  for (int r = 0; r < 4; r++) ll[r] = 1.0f / ll[r];
#pragma unroll
  for (int nd = 0; nd < 16; nd++)
#pragma unroll
    for (int r = 0; r < 4; r++) {
      float v = oacc[nd][r] * ll[r];
      Ao[((size_t)(b * 2048 + qrow0 + lk * 4 + r)) * 2048 + h * 256 + nd * 16 + lr] = f2bf(v);
    }
}

// ---------------- launch ----------------
// Workspace layout with lifetime-based reuse (peak ≈ 74 MB):
//   region0 [0, 33.55M):  QKV  -> later Ao [0,16.78M) + WoT [16.78M,27.26M)
//   region1 [33.55M, 54.53M): Xb -> later Qh
//   region2 [54.53M, 75.50M): WqT -> later Kh + VT
//   region3 [75.50M, 77.59M): ct, st
extern "C" void kernel_launch(void* const* d_in, const int* in_sizes, int n_in,
                              void* d_out, int out_size, void* d_ws, size_t ws_size,
                              hipStream_t stream) {
  const float* hs   = (const float*)d_in[0];
  const float* wqkv = (const float*)d_in[1];
  const float* wo   = (const float*)d_in[2];
  const float* qnw  = (const float*)d_in[3];
  const float* knw  = (const float*)d_in[4];
  const int*   pos  = (const int*)d_in[5];
  float* out = (float*)d_out;  // reference output dtype is float32

  char* base = (char*)d_ws;
  const size_t OFF_R0 = 0;
  const size_t OFF_R1 = 33554432;
  const size_t OFF_R2 = 54525952;
  const size_t OFF_R3 = 75497472;

  unsigned short* QKV = (unsigned short*)(base + OFF_R0);
  unsigned short* Ao  = (unsigned short*)(base + OFF_R0);
  unsigned short* WoT = (unsigned short*)(base + OFF_R0 + 16777216);
  unsigned short* Xb  = (unsigned short*)(base + OFF_R1);
  unsigned short* Qh  = (unsigned short*)(base + OFF_R1);
  unsigned short* WqT = (unsigned short*)(base + OFF_R2);
  unsigned short* Kh  = (unsigned short*)(base + OFF_R2);
  unsigned short* VT  = (unsigned short*)(base + OFF_R2 + 8388608);
  float* ct = (float*)(base + OFF_R3);
  float* st = (float*)(base + OFF_R3 + 1048576);

  k_cvt_bf16<<<10240, 256, 0, stream>>>(hs, Xb, 2621440, pos, ct, st);         // + fused rope table
  k_transpose_w<<<dim3(128, 80), 256, 0, stream>>>(wqkv, WqT, 2560, 4096);
  k_gemm256<false><<<256, 512, 0, stream>>>(Xb, WqT, QKV, 4096, 4096, 2560);   // Xb, WqT dead after
  k_norm_rope<<<12288, 256, 0, stream>>>(QKV, qnw, knw, ct, st, Qh, Kh);       // Qh over Xb, Kh over WqT
  k_vtrans<<<1024, 256, 0, stream>>>(QKV, VT);                                 // QKV dead after
  k_transpose_w<<<dim3(80, 64), 256, 0, stream>>>(wo, WoT, 2048, 2560);        // WoT over QKV tail
  k_attn<<<256, 512, 0, stream>>>(Qh, Kh, VT, pos, Ao);                        // Ao over QKV head
  k_gemm256<true><<<160, 512, 0, stream>>>(Ao, WoT, out, 4096, 2560, 2048);    // fp32 out
}

// Round 20
// 225.260 us; speedup vs baseline: 1.1064x; 1.0109x over previous
//
#include <hip/hip_runtime.h>
#include <hip/hip_bf16.h>
#include <stdint.h>

// Problem constants
// B=2 S=2048 HID=2560 H=8 HKV=4 D=256 GROUPS=2 window=512
#define QSCALE 0.09016844005555459f  // (1/16) * log2(e)

typedef __attribute__((ext_vector_type(4))) float f32x4;
typedef __attribute__((ext_vector_type(8))) __bf16 bf16x8;
typedef __attribute__((ext_vector_type(8))) unsigned short ushort8;

static __device__ __forceinline__ float bf2f(unsigned short v) {
  union { unsigned u; float f; } x; x.u = ((unsigned)v) << 16; return x.f;
}
static __device__ __forceinline__ unsigned short f2bf(float f) {
  union { float f; unsigned u; } x; x.f = f;
  unsigned r = x.u + 0x7fffu + ((x.u >> 16) & 1u);
  return (unsigned short)(r >> 16);
}
static __device__ __forceinline__ void gload16(const void* g, void* l) {
  __builtin_amdgcn_global_load_lds((const __attribute__((address_space(1))) void*)g,
                                   (__attribute__((address_space(3))) void*)l, 16, 0, 0);
}
#define SBAR() __builtin_amdgcn_s_barrier()

// ---------------- fp32 -> bf16 elementwise + fused rope table ----------------
__global__ __launch_bounds__(256) void k_cvt_bf16(const float* __restrict__ in,
                                                  unsigned short* __restrict__ out, int n4,
                                                  const int* __restrict__ pos,
                                                  float* __restrict__ ct,
                                                  float* __restrict__ st) {
  int i = blockIdx.x * 256 + threadIdx.x;
  if (blockIdx.x < 1024) {                  // rope table: S*128 = 262144 entries
    int idx = i;
    int s = idx >> 7, j = idx & 127;
    float inv = exp2f((float)j * (-13.287712379549449f / 128.0f));  // 10000^(-j/128)
    float ang = (float)pos[s] * inv;
    float sv, cv;
    sincosf(ang, &sv, &cv);
    ct[idx] = cv; st[idx] = sv;
  }
  if (i >= n4) return;
  float4 v = ((const float4*)in)[i];
  ushort4 o; o.x = f2bf(v.x); o.y = f2bf(v.y); o.z = f2bf(v.z); o.w = f2bf(v.w);
  ((ushort4*)out)[i] = o;
}

// ---------------- transpose fp32 [R][C] -> bf16 [C][R] ----------------
__global__ __launch_bounds__(256) void k_transpose_w(const float* __restrict__ in,
                                                     unsigned short* __restrict__ out,
                                                     int R, int C) {
  __shared__ float tile[32][33];
  int c0 = blockIdx.x * 32, r0 = blockIdx.y * 32;
  int tx = threadIdx.x & 31, ty = threadIdx.x >> 5;  // 32 x 8
#pragma unroll
  for (int i = 0; i < 4; i++)
    tile[ty + 8*i][tx] = in[(size_t)(r0 + ty + 8*i) * C + c0 + tx];
  __syncthreads();
#pragma unroll
  for (int i = 0; i < 4; i++)
    out[(size_t)(c0 + ty + 8*i) * R + r0 + tx] = f2bf(tile[tx][ty + 8*i]);
}

// ---------------- 256x256 bf16 GEMM (r10 structure — best measured, FINAL) ----------------
// BK=32, ring of 4 LDS slots (128KB), 8 waves (2Mx4N), counted vmcnt(8) (never
// 0 mid-loop), ONE raw s_barrier per K-step, setprio around the 32-MFMA cluster.
// Ledger: RAW: entering step kt, tile kt in LDS for ALL waves (tail of kt-1 did
// vmcnt(8) + SBAR). WAR: stage(kt+3) -> slot (kt-1)&3; readers were step kt-1's
// ds_reads, complete before its MFMA (lgkm) which precedes the tail SBAR.
// Bank swizzle (verified 0-conflict): chunk ^= (row>>1)&3, inverse-swizzled
// GLOBAL source + swizzled ds_read (rule #21). Requires nt % 4 == 0, nt >= 8.
template <bool F32OUT>
__global__ __launch_bounds__(512, 1) void k_gemm256(const unsigned short* __restrict__ A,
                                                    const unsigned short* __restrict__ Bt,
                                                    void* __restrict__ Cm,
                                                    int M, int N, int K) {
  __shared__ __align__(16) unsigned short ldsA[4][8192];  // 4 slots x [256][32] bf16 (swizzled)
  __shared__ __align__(16) unsigned short ldsB[4][8192];
  const int nbn = N >> 8;
  int bid = blockIdx.x;
  int nwg = gridDim.x;
  if ((nwg & 7) == 0) {                    // XCD-aware swizzle (bijective: nwg%8==0)
    int cpx = nwg >> 3;
    bid = (bid & 7) * cpx + (bid >> 3);
  }
  const int bm = bid / nbn, bn = bid % nbn;
  const int tid = threadIdx.x;
  const int w = tid >> 6, l = tid & 63;
  const int wm = w >> 2, wn = w & 3;
  const int lr = l & 15, lk = l >> 4;
  const int nt = K >> 5;                   // BK = 32; nt % 4 == 0, nt >= 8

  const int rL = tid >> 2;
  const int swc = ((tid & 3) ^ ((tid >> 3) & 3)) << 3;
  const unsigned short* Ag = A + (size_t)(bm * 256 + rL) * K + swc;
  const unsigned short* Bg = Bt + (size_t)(bn * 256 + rL) * K + swc;
  const int ldsoff = w * 512;
  const int wb = ((lk ^ ((lr >> 1) & 3)) << 3);
  const int arow0 = wm * 128 + lr;
  const int brow0 = wn * 64 + lr;

  f32x4 acc[8][4] = {};

#define STAGE_A(kt_, s_) do { \
    gload16(Ag + (size_t)(kt_) * 32,                    (char*)&ldsA[s_][ldsoff]); \
    gload16(Ag + (size_t)(kt_) * 32 + (size_t)128 * K,  (char*)&ldsA[s_][4096 + ldsoff]); } while (0)
#define STAGE_B(kt_, s_) do { \
    gload16(Bg + (size_t)(kt_) * 32,                    (char*)&ldsB[s_][ldsoff]); \
    gload16(Bg + (size_t)(kt_) * 32 + (size_t)128 * K,  (char*)&ldsB[s_][4096 + ldsoff]); } while (0)

#define KSTEP(kt_, S_, PF_, VMC_, TAILBAR_) do { \
    bf16x8 af[8], bf[4]; \
    _Pragma("unroll") \
    for (int i = 0; i < 8; ++i) \
      af[i] = *(const bf16x8*)&ldsA[S_][((arow0 + i * 16) << 5) + wb]; \
    _Pragma("unroll") \
    for (int j = 0; j < 4; ++j) \
      bf[j] = *(const bf16x8*)&ldsB[S_][((brow0 + j * 16) << 5) + wb]; \
    if (PF_) { STAGE_A((kt_) + 3, ((S_) + 3) & 3); STAGE_B((kt_) + 3, ((S_) + 3) & 3); } \
    __builtin_amdgcn_s_setprio(1); \
    _Pragma("unroll") \
    for (int i = 0; i < 8; ++i) \
      _Pragma("unroll") \
      for (int j = 0; j < 4; ++j) \
        acc[i][j] = __builtin_amdgcn_mfma_f32_16x16x32_bf16(af[i], bf[j], acc[i][j], 0, 0, 0); \
    __builtin_amdgcn_s_setprio(0); \
    if ((VMC_) == 8)      { asm volatile("s_waitcnt vmcnt(8)" ::: "memory"); } \
    else if ((VMC_) == 4) { asm volatile("s_waitcnt vmcnt(4)" ::: "memory"); } \
    else if ((VMC_) == 0) { asm volatile("s_waitcnt vmcnt(0)" ::: "memory"); } \
    if (TAILBAR_) SBAR(); \
  } while (0)

  STAGE_A(0, 0); STAGE_B(0, 0);
  STAGE_A(1, 1); STAGE_B(1, 1);
  STAGE_A(2, 2); STAGE_B(2, 2);
  asm volatile("s_waitcnt vmcnt(8)" ::: "memory");
  SBAR();

  const int ng = nt >> 2;
  for (int g = 0; g < ng - 1; ++g) {
    const int kt0 = g << 2;
    KSTEP(kt0 + 0, 0, true, 8, true);
    KSTEP(kt0 + 1, 1, true, 8, true);
    KSTEP(kt0 + 2, 2, true, 8, true);
    KSTEP(kt0 + 3, 3, true, 8, true);
  }
  {
    const int kt0 = nt - 4;
    KSTEP(kt0 + 0, 0, true, 8, true);
    KSTEP(kt0 + 1, 1, false, 4, true);
    KSTEP(kt0 + 2, 2, false, 0, true);
    KSTEP(kt0 + 3, 3, false, -1, false);
  }
#undef KSTEP
#undef STAGE_A
#undef STAGE_B

#pragma unroll
  for (int i = 0; i < 8; ++i)
#pragma unroll
    for (int j = 0; j < 4; ++j) {
      int row = bm * 256 + wm * 128 + i * 16 + lk * 4;
      int col = bn * 256 + wn * 64 + j * 16 + lr;
#pragma unroll
      for (int r = 0; r < 4; ++r) {
        if constexpr (F32OUT)
          ((float*)Cm)[(size_t)(row + r) * N + col] = acc[i][j][r];
        else
          ((unsigned short*)Cm)[(size_t)(row + r) * N + col] = f2bf(acc[i][j][r]);
      }
    }
}

// ---------------- fused RMSNorm+RoPE (Q,K) + V transpose, single launch ----------------
// r20: k_vtrans merged as extra blocks (bid >= 12288). Both paths are pure
// readers of QKV; writes disjoint (Qh->R1, Kh->R2[0,8.39M), VT->R2[8.39M,...)).
__global__ __launch_bounds__(256) void k_norm_rope(
    const unsigned short* __restrict__ qkv,
    const float* __restrict__ qw, const float* __restrict__ kw,
    const float* __restrict__ ct, const float* __restrict__ st,
    unsigned short* __restrict__ Qh, unsigned short* __restrict__ Kh,
    unsigned short* __restrict__ VT) {
  if (blockIdx.x >= 12288) {
    // ---- V transpose path (was k_vtrans): vbid = [b][hk][stile(32)][dt(4)] ----
    __shared__ __align__(16) unsigned short tile[64][72];  // 144B rows
    int vbid = blockIdx.x - 12288;
    int dt = vbid & 3, stile = (vbid >> 2) & 31, hk = (vbid >> 7) & 3, b = vbid >> 9;
    int s0 = stile * 64, d0 = dt * 64;
    int t = threadIdx.x;
#pragma unroll
    for (int i = 0; i < 2; i++) {
      int flat = i * 256 + t;
      int sl = flat >> 3, dc = flat & 7;
      ushort8 v = *(const ushort8*)&qkv[(size_t)(b * 2048 + s0 + sl) * 4096 + 3072 + hk * 256 + d0 + dc * 8];
      *(ushort8*)&tile[sl][dc * 8] = v;
    }
    __syncthreads();
#pragma unroll
    for (int i = 0; i < 2; i++) {
      int flat = i * 256 + t;
      int dl = flat >> 3, sc = flat & 7;
      ushort8 v;
#pragma unroll
      for (int j = 0; j < 8; j++) v[j] = tile[sc * 8 + j][dl];
      int dg = d0 + dl;
      int chg = (s0 >> 3) + sc;
      int swc = chg ^ (dg & 7);
      *(ushort8*)&VT[((size_t)(b * 4 + hk) * 256 + dg) * 2048 + swc * 8] = v;
    }
    return;
  }
  // ---- RMSNorm + RoPE path: one wave per (b,s,head) row ----
  int gwid = (blockIdx.x * 256 + threadIdx.x) >> 6;  // 0 .. 4096*12-1
  int l = threadIdx.x & 63;
  int head = gwid % 12;
  int bs = gwid / 12;
  int b = bs >> 11, s = bs & 2047;
  bool isq = head < 8;
  int col = isq ? head * 256 : 2048 + (head - 8) * 256;
  const unsigned short* src = qkv + (size_t)bs * 4096 + col;
  int d0 = l * 4;
  ushort4 u = *(const ushort4*)(src + d0);
  float x0 = bf2f(u.x), x1 = bf2f(u.y), x2 = bf2f(u.z), x3 = bf2f(u.w);
  float ss = x0 * x0 + x1 * x1 + x2 * x2 + x3 * x3;
#pragma unroll
  for (int off = 32; off > 0; off >>= 1) ss += __shfl_xor(ss, off);
  float inv = rsqrtf(ss * (1.0f / 256.0f) + 1e-6f);
  const float* wv = isq ? qw : kw;
  float4 w4 = *(const float4*)(wv + d0);
  float y0 = x0 * inv * (1.0f + w4.x);
  float y1 = x1 * inv * (1.0f + w4.y);
  float y2 = x2 * inv * (1.0f + w4.z);
  float y3 = x3 * inv * (1.0f + w4.w);
  int fb = (l & 31) * 4;
  float4 c4 = *(const float4*)(ct + s * 128 + fb);
  float4 s4 = *(const float4*)(st + s * 128 + fb);
  float p0 = __shfl_xor(y0, 32), p1 = __shfl_xor(y1, 32);
  float p2 = __shfl_xor(y2, 32), p3 = __shfl_xor(y3, 32);
  float sg = (l < 32) ? -1.0f : 1.0f;
  float o0 = y0 * c4.x + sg * p0 * s4.x;
  float o1 = y1 * c4.y + sg * p1 * s4.y;
  float o2 = y2 * c4.z + sg * p2 * s4.z;
  float o3 = y3 * c4.w + sg * p3 * s4.w;
  if (isq) {
    o0 *= QSCALE; o1 *= QSCALE; o2 *= QSCALE; o3 *= QSCALE;
    unsigned short* dst = Qh + (((size_t)(b * 8 + head)) * 2048 + s) * 256 + d0;
    ushort4 o; o.x = f2bf(o0); o.y = f2bf(o1); o.z = f2bf(o2); o.w = f2bf(o3);
    *(ushort4*)dst = o;
  } else {
    int hk = head - 8;
    int ch = d0 >> 3;
    int dsw = ((ch ^ (s & 7)) << 3) | (d0 & 7);
    unsigned short* dst = Kh + (((size_t)(b * 4 + hk)) * 2048 + s) * 256 + dsw;
    ushort4 o; o.x = f2bf(o0); o.y = f2bf(o1); o.z = f2bf(o2); o.w = f2bf(o3);
    *(ushort4*)dst = o;
  }
}

// ---------------- windowed flash attention, GQA-paired + double-buffered ----------------
// K/V tiles double-buffered in LDS; counted vmcnt(8) keeps next tile's loads in
// flight across barriers; raw SBAR (no __syncthreads -> no forced vmcnt(0)).
__global__ __launch_bounds__(512) void k_attn(
    const unsigned short* __restrict__ Qh,
    const unsigned short* __restrict__ Kh,
    const unsigned short* __restrict__ VT,
    const int* __restrict__ pos,
    unsigned short* __restrict__ Ao) {
  __shared__ __align__(16) unsigned short Ks[2][64 * 256];
  __shared__ __align__(16) unsigned short Vs[2][256 * 64];
  __shared__ __align__(16) unsigned short Ps[8][16 * 72];
  int bid = blockIdx.x;
  int qt = bid & 31, hk = (bid >> 5) & 3, b = bid >> 7;
  int t = threadIdx.x, w = t >> 6, l = t & 63;
  int lr = l & 15, lk = l >> 4;
  int h = hk * 2 + (w >> 2);
  int q0 = qt * 64, qrow0 = q0 + (w & 3) * 16;
  const unsigned short* qbase = Qh + (((size_t)(b * 8 + h)) * 2048 + (qrow0 + lr)) * 256;
  bf16x8 qf[8];
#pragma unroll
  for (int c = 0; c < 8; c++) qf[c] = *(const bf16x8*)&qbase[c * 32 + lk * 8];
  int pq[4];
#pragma unroll
  for (int r = 0; r < 4; r++) pq[r] = pos[qrow0 + lk * 4 + r];
  float m[4], ll[4];
  f32x4 oacc[16];
  f32x4 zero4 = {0.f, 0.f, 0.f, 0.f};
#pragma unroll
  for (int r = 0; r < 4; r++) { m[r] = -1e30f; ll[r] = 0.0f; }
#pragma unroll
  for (int nd = 0; nd < 16; nd++) oacc[nd] = zero4;
  const char* Kbase = (const char*)(Kh + ((size_t)(b * 4 + hk)) * 2048 * 256);
  const char* Vbase = (const char*)(VT + ((size_t)(b * 4 + hk)) * 256 * 2048);
  int jlo = q0 - 511; if (jlo < 0) jlo = 0; jlo &= ~63;
  const int ntj = ((q0 + 64) - jlo) >> 6;

#define ASTAGE(tj_) do { \
    const int j0_ = jlo + (tj_) * 64; \
    char* kd_ = (char*)Ks[(tj_) & 1]; \
    char* vd_ = (char*)Vs[(tj_) & 1]; \
    _Pragma("unroll") \
    for (int i = 0; i < 4; i++) \
      gload16(Kbase + (size_t)j0_ * 512 + i * 8192 + t * 16, kd_ + i * 8192 + w * 1024); \
    _Pragma("unroll") \
    for (int i = 0; i < 4; i++) { \
      int off_ = i * 8192 + t * 16; \
      int d_ = off_ >> 7, rb_ = off_ & 127; \
      gload16(Vbase + (size_t)d_ * 4096 + j0_ * 2 + rb_, vd_ + i * 8192 + w * 1024); \
    } \
  } while (0)

  ASTAGE(0);
  for (int tj = 0; tj < ntj; ++tj) {
    const int j0 = jlo + tj * 64;
    const char* Kb = (const char*)Ks[tj & 1];
    const char* Vb = (const char*)Vs[tj & 1];
    if (tj + 1 < ntj) {
      ASTAGE(tj + 1);
      asm volatile("s_waitcnt vmcnt(8)" ::: "memory");
    } else {
      asm volatile("s_waitcnt vmcnt(0)" ::: "memory");
    }
    SBAR();
    f32x4 sacc[4];
#pragma unroll
    for (int n = 0; n < 4; n++) sacc[n] = zero4;
    __builtin_amdgcn_s_setprio(1);
#pragma unroll
    for (int n = 0; n < 4; n++) {
      int key = n * 16 + lr;
      int sw = (key & 7) << 4;
#pragma unroll
      for (int c = 0; c < 8; c++) {
        bf16x8 kf = *(const bf16x8*)(Kb + key * 512 + ((c * 64 + lk * 16) ^ sw));
        sacc[n] = __builtin_amdgcn_mfma_f32_16x16x32_bf16(qf[c], kf, sacc[n], 0, 0, 0);
      }
    }
    __builtin_amdgcn_s_setprio(0);
    int pk[4];
#pragma unroll
    for (int n = 0; n < 4; n++) pk[n] = pos[j0 + n * 16 + lr];
#pragma unroll
    for (int n = 0; n < 4; n++)
#pragma unroll
      for (int r = 0; r < 4; r++) {
        int dq = pq[r] - pk[n];
        if (!(dq >= 0 && dq < 512)) sacc[n][r] = -1e30f;
      }
    float tm[4], rs[4], mn[4], corr[4];
#pragma unroll
    for (int r = 0; r < 4; r++)
      tm[r] = fmaxf(fmaxf(sacc[0][r], sacc[1][r]), fmaxf(sacc[2][r], sacc[3][r]));
#pragma unroll
    for (int d = 1; d < 16; d <<= 1)
#pragma unroll
      for (int r = 0; r < 4; r++) tm[r] = fmaxf(tm[r], __shfl_xor(tm[r], d));
#pragma unroll
    for (int r = 0; r < 4; r++) {
      mn[r] = fmaxf(m[r], tm[r]);
      corr[r] = exp2f(m[r] - mn[r]);
      rs[r] = 0.f;
    }
#pragma unroll
    for (int n = 0; n < 4; n++)
#pragma unroll
      for (int r = 0; r < 4; r++) {
        float sv = sacc[n][r];
        float p = (sv > -1e29f) ? exp2f(sv - mn[r]) : 0.0f;
        sacc[n][r] = p;
        rs[r] += p;
      }
#pragma unroll
    for (int d = 1; d < 16; d <<= 1)
#pragma unroll
      for (int r = 0; r < 4; r++) rs[r] += __shfl_xor(rs[r], d);
#pragma unroll
    for (int r = 0; r < 4; r++) { ll[r] = ll[r] * corr[r] + rs[r]; m[r] = mn[r]; }
#pragma unroll
    for (int nd = 0; nd < 16; nd++)
#pragma unroll
      for (int r = 0; r < 4; r++) oacc[nd][r] *= corr[r];
#pragma unroll
    for (int n = 0; n < 4; n++)
#pragma unroll
      for (int r = 0; r < 4; r++)
        Ps[w][(lk * 4 + r) * 72 + n * 16 + lr] = f2bf(sacc[n][r]);
#pragma unroll
    for (int c2 = 0; c2 < 2; c2++) {
      bf16x8 pf = *(const bf16x8*)&Ps[w][lr * 72 + c2 * 32 + lk * 8];
      __builtin_amdgcn_s_setprio(1);
#pragma unroll
      for (int nd = 0; nd < 16; nd++) {
        int dr = nd * 16 + lr;
        bf16x8 vf = *(const bf16x8*)(Vb + dr * 128 + ((c2 * 64 + lk * 16) ^ ((dr & 7) << 4)));
        oacc[nd] = __builtin_amdgcn_mfma_f32_16x16x32_bf16(pf, vf, oacc[nd], 0, 0, 0);
      }
      __builtin_amdgcn_s_setprio(0);
    }
    SBAR();
  }
#undef ASTAGE
#pragma unroll
  for (int r = 0; r < 4; r++) ll[r] = 1.0f / ll[r];
#pragma unroll
  for (int nd = 0; nd < 16; nd++)
#pragma unroll
    for (int r = 0; r < 4; r++) {
      float v = oacc[nd][r] * ll[r];
      Ao[((size_t)(b * 2048 + qrow0 + lk * 4 + r)) * 2048 + h * 256 + nd * 16 + lr] = f2bf(v);
    }
}

// ---------------- launch ----------------
// Workspace layout with lifetime-based reuse (peak ≈ 74 MB):
//   region0 [0, 33.55M):  QKV  -> later Ao [0,16.78M) + WoT [16.78M,27.26M)
//   region1 [33.55M, 54.53M): Xb -> later Qh
//   region2 [54.53M, 75.50M): WqT -> later Kh + VT
//   region3 [75.50M, 77.59M): ct, st
extern "C" void kernel_launch(void* const* d_in, const int* in_sizes, int n_in,
                              void* d_out, int out_size, void* d_ws, size_t ws_size,
                              hipStream_t stream) {
  const float* hs   = (const float*)d_in[0];
  const float* wqkv = (const float*)d_in[1];
  const float* wo   = (const float*)d_in[2];
  const float* qnw  = (const float*)d_in[3];
  const float* knw  = (const float*)d_in[4];
  const int*   pos  = (const int*)d_in[5];
  float* out = (float*)d_out;  // reference output dtype is float32

  char* base = (char*)d_ws;
  const size_t OFF_R0 = 0;
  const size_t OFF_R1 = 33554432;
  const size_t OFF_R2 = 54525952;
  const size_t OFF_R3 = 75497472;

  unsigned short* QKV = (unsigned short*)(base + OFF_R0);
  unsigned short* Ao  = (unsigned short*)(base + OFF_R0);
  unsigned short* WoT = (unsigned short*)(base + OFF_R0 + 16777216);
  unsigned short* Xb  = (unsigned short*)(base + OFF_R1);
  unsigned short* Qh  = (unsigned short*)(base + OFF_R1);
  unsigned short* WqT = (unsigned short*)(base + OFF_R2);
  unsigned short* Kh  = (unsigned short*)(base + OFF_R2);
  unsigned short* VT  = (unsigned short*)(base + OFF_R2 + 8388608);
  float* ct = (float*)(base + OFF_R3);
  float* st = (float*)(base + OFF_R3 + 1048576);

  k_cvt_bf16<<<10240, 256, 0, stream>>>(hs, Xb, 2621440, pos, ct, st);          // + fused rope table
  k_transpose_w<<<dim3(128, 80), 256, 0, stream>>>(wqkv, WqT, 2560, 4096);
  k_gemm256<false><<<256, 512, 0, stream>>>(Xb, WqT, QKV, 4096, 4096, 2560);    // Xb, WqT dead after
  k_norm_rope<<<13312, 256, 0, stream>>>(QKV, qnw, knw, ct, st, Qh, Kh, VT);    // + fused V transpose
  k_transpose_w<<<dim3(80, 64), 256, 0, stream>>>(wo, WoT, 2048, 2560);         // WoT over QKV tail
  k_attn<<<256, 512, 0, stream>>>(Qh, Kh, VT, pos, Ao);                         // Ao over QKV head
  k_gemm256<true><<<160, 512, 0, stream>>>(Ao, WoT, out, 4096, 2560, 2048);     // fp32 out
}

// Round 21
// 223.721 us; speedup vs baseline: 1.1140x; 1.0069x over previous
//
#include <hip/hip_runtime.h>
#include <hip/hip_bf16.h>
#include <stdint.h>

// Problem constants
// B=2 S=2048 HID=2560 H=8 HKV=4 D=256 GROUPS=2 window=512
#define QSCALE 0.09016844005555459f  // (1/16) * log2(e)

typedef __attribute__((ext_vector_type(4))) float f32x4;
typedef __attribute__((ext_vector_type(8))) __bf16 bf16x8;
typedef __attribute__((ext_vector_type(8))) unsigned short ushort8;

static __device__ __forceinline__ float bf2f(unsigned short v) {
  union { unsigned u; float f; } x; x.u = ((unsigned)v) << 16; return x.f;
}
static __device__ __forceinline__ unsigned short f2bf(float f) {
  union { float f; unsigned u; } x; x.f = f;
  unsigned r = x.u + 0x7fffu + ((x.u >> 16) & 1u);
  return (unsigned short)(r >> 16);
}
static __device__ __forceinline__ void gload16(const void* g, void* l) {
  __builtin_amdgcn_global_load_lds((const __attribute__((address_space(1))) void*)g,
                                   (__attribute__((address_space(3))) void*)l, 16, 0, 0);
}
#define SBAR() __builtin_amdgcn_s_barrier()

// ---------------- head-of-stream prep, single launch ----------------
// r21: blocks [0,10240): fp32->bf16 cvt of hidden (+ rope table in blocks
// [0,1024)); blocks [10240,20480): wqkv transpose fp32[2560][4096] ->
// bf16[4096][2560]. Disjoint reads (hs/pos vs wqkv) and writes (Xb/ct/st vs
// WqT). Launch count now at the dependency-graph minimum (5).
__global__ __launch_bounds__(256) void k_prep(const float* __restrict__ in,
                                              unsigned short* __restrict__ out, int n4,
                                              const int* __restrict__ pos,
                                              float* __restrict__ ct,
                                              float* __restrict__ st,
                                              const float* __restrict__ w_in,
                                              unsigned short* __restrict__ w_out) {
  if (blockIdx.x >= 10240) {
    // ---- wqkv transpose path: R=2560 rows, C=4096 cols ----
    __shared__ float tile[32][33];
    int tbid = blockIdx.x - 10240;
    int c0 = (tbid & 127) * 32, r0 = (tbid >> 7) * 32;
    int tx = threadIdx.x & 31, ty = threadIdx.x >> 5;  // 32 x 8
#pragma unroll
    for (int i = 0; i < 4; i++)
      tile[ty + 8*i][tx] = w_in[(size_t)(r0 + ty + 8*i) * 4096 + c0 + tx];
    __syncthreads();
#pragma unroll
    for (int i = 0; i < 4; i++)
      w_out[(size_t)(c0 + ty + 8*i) * 2560 + r0 + tx] = f2bf(tile[tx][ty + 8*i]);
    return;
  }
  int i = blockIdx.x * 256 + threadIdx.x;
  if (blockIdx.x < 1024) {                  // rope table: S*128 = 262144 entries
    int idx = i;
    int s = idx >> 7, j = idx & 127;
    float inv = exp2f((float)j * (-13.287712379549449f / 128.0f));  // 10000^(-j/128)
    float ang = (float)pos[s] * inv;
    float sv, cv;
    sincosf(ang, &sv, &cv);
    ct[idx] = cv; st[idx] = sv;
  }
  if (i >= n4) return;
  float4 v = ((const float4*)in)[i];
  ushort4 o; o.x = f2bf(v.x); o.y = f2bf(v.y); o.z = f2bf(v.z); o.w = f2bf(v.w);
  ((ushort4*)out)[i] = o;
}

// ---------------- transpose fp32 [R][C] -> bf16 [C][R] (w_o only) ----------------
__global__ __launch_bounds__(256) void k_transpose_w(const float* __restrict__ in,
                                                     unsigned short* __restrict__ out,
                                                     int R, int C) {
  __shared__ float tile[32][33];
  int c0 = blockIdx.x * 32, r0 = blockIdx.y * 32;
  int tx = threadIdx.x & 31, ty = threadIdx.x >> 5;  // 32 x 8
#pragma unroll
  for (int i = 0; i < 4; i++)
    tile[ty + 8*i][tx] = in[(size_t)(r0 + ty + 8*i) * C + c0 + tx];
  __syncthreads();
#pragma unroll
  for (int i = 0; i < 4; i++)
    out[(size_t)(c0 + ty + 8*i) * R + r0 + tx] = f2bf(tile[tx][ty + 8*i]);
}

// ---------------- 256x256 bf16 GEMM (r10 structure — best measured, FINAL) ----------------
// BK=32, ring of 4 LDS slots (128KB), 8 waves (2Mx4N), counted vmcnt(8) (never
// 0 mid-loop), ONE raw s_barrier per K-step, setprio around the 32-MFMA cluster.
// Ledger: RAW: entering step kt, tile kt in LDS for ALL waves (tail of kt-1 did
// vmcnt(8) + SBAR). WAR: stage(kt+3) -> slot (kt-1)&3; readers were step kt-1's
// ds_reads, complete before its MFMA (lgkm) which precedes the tail SBAR.
// Bank swizzle (verified 0-conflict): chunk ^= (row>>1)&3, inverse-swizzled
// GLOBAL source + swizzled ds_read (rule #21). Requires nt % 4 == 0, nt >= 8.
template <bool F32OUT>
__global__ __launch_bounds__(512, 1) void k_gemm256(const unsigned short* __restrict__ A,
                                                    const unsigned short* __restrict__ Bt,
                                                    void* __restrict__ Cm,
                                                    int M, int N, int K) {
  __shared__ __align__(16) unsigned short ldsA[4][8192];  // 4 slots x [256][32] bf16 (swizzled)
  __shared__ __align__(16) unsigned short ldsB[4][8192];
  const int nbn = N >> 8;
  int bid = blockIdx.x;
  int nwg = gridDim.x;
  if ((nwg & 7) == 0) {                    // XCD-aware swizzle (bijective: nwg%8==0)
    int cpx = nwg >> 3;
    bid = (bid & 7) * cpx + (bid >> 3);
  }
  const int bm = bid / nbn, bn = bid % nbn;
  const int tid = threadIdx.x;
  const int w = tid >> 6, l = tid & 63;
  const int wm = w >> 2, wn = w & 3;
  const int lr = l & 15, lk = l >> 4;
  const int nt = K >> 5;                   // BK = 32; nt % 4 == 0, nt >= 8

  const int rL = tid >> 2;
  const int swc = ((tid & 3) ^ ((tid >> 3) & 3)) << 3;
  const unsigned short* Ag = A + (size_t)(bm * 256 + rL) * K + swc;
  const unsigned short* Bg = Bt + (size_t)(bn * 256 + rL) * K + swc;
  const int ldsoff = w * 512;
  const int wb = ((lk ^ ((lr >> 1) & 3)) << 3);
  const int arow0 = wm * 128 + lr;
  const int brow0 = wn * 64 + lr;

  f32x4 acc[8][4] = {};

#define STAGE_A(kt_, s_) do { \
    gload16(Ag + (size_t)(kt_) * 32,                    (char*)&ldsA[s_][ldsoff]); \
    gload16(Ag + (size_t)(kt_) * 32 + (size_t)128 * K,  (char*)&ldsA[s_][4096 + ldsoff]); } while (0)
#define STAGE_B(kt_, s_) do { \
    gload16(Bg + (size_t)(kt_) * 32,                    (char*)&ldsB[s_][ldsoff]); \
    gload16(Bg + (size_t)(kt_) * 32 + (size_t)128 * K,  (char*)&ldsB[s_][4096 + ldsoff]); } while (0)

#define KSTEP(kt_, S_, PF_, VMC_, TAILBAR_) do { \
    bf16x8 af[8], bf[4]; \
    _Pragma("unroll") \
    for (int i = 0; i < 8; ++i) \
      af[i] = *(const bf16x8*)&ldsA[S_][((arow0 + i * 16) << 5) + wb]; \
    _Pragma("unroll") \
    for (int j = 0; j < 4; ++j) \
      bf[j] = *(const bf16x8*)&ldsB[S_][((brow0 + j * 16) << 5) + wb]; \
    if (PF_) { STAGE_A((kt_) + 3, ((S_) + 3) & 3); STAGE_B((kt_) + 3, ((S_) + 3) & 3); } \
    __builtin_amdgcn_s_setprio(1); \
    _Pragma("unroll") \
    for (int i = 0; i < 8; ++i) \
      _Pragma("unroll") \
      for (int j = 0; j < 4; ++j) \
        acc[i][j] = __builtin_amdgcn_mfma_f32_16x16x32_bf16(af[i], bf[j], acc[i][j], 0, 0, 0); \
    __builtin_amdgcn_s_setprio(0); \
    if ((VMC_) == 8)      { asm volatile("s_waitcnt vmcnt(8)" ::: "memory"); } \
    else if ((VMC_) == 4) { asm volatile("s_waitcnt vmcnt(4)" ::: "memory"); } \
    else if ((VMC_) == 0) { asm volatile("s_waitcnt vmcnt(0)" ::: "memory"); } \
    if (TAILBAR_) SBAR(); \
  } while (0)

  STAGE_A(0, 0); STAGE_B(0, 0);
  STAGE_A(1, 1); STAGE_B(1, 1);
  STAGE_A(2, 2); STAGE_B(2, 2);
  asm volatile("s_waitcnt vmcnt(8)" ::: "memory");
  SBAR();

  const int ng = nt >> 2;
  for (int g = 0; g < ng - 1; ++g) {
    const int kt0 = g << 2;
    KSTEP(kt0 + 0, 0, true, 8, true);
    KSTEP(kt0 + 1, 1, true, 8, true);
    KSTEP(kt0 + 2, 2, true, 8, true);
    KSTEP(kt0 + 3, 3, true, 8, true);
  }
  {
    const int kt0 = nt - 4;
    KSTEP(kt0 + 0, 0, true, 8, true);
    KSTEP(kt0 + 1, 1, false, 4, true);
    KSTEP(kt0 + 2, 2, false, 0, true);
    KSTEP(kt0 + 3, 3, false, -1, false);
  }
#undef KSTEP
#undef STAGE_A
#undef STAGE_B

#pragma unroll
  for (int i = 0; i < 8; ++i)
#pragma unroll
    for (int j = 0; j < 4; ++j) {
      int row = bm * 256 + wm * 128 + i * 16 + lk * 4;
      int col = bn * 256 + wn * 64 + j * 16 + lr;
#pragma unroll
      for (int r = 0; r < 4; ++r) {
        if constexpr (F32OUT)
          ((float*)Cm)[(size_t)(row + r) * N + col] = acc[i][j][r];
        else
          ((unsigned short*)Cm)[(size_t)(row + r) * N + col] = f2bf(acc[i][j][r]);
      }
    }
}

// ---------------- fused RMSNorm+RoPE (Q,K) + V transpose, single launch ----------------
__global__ __launch_bounds__(256) void k_norm_rope(
    const unsigned short* __restrict__ qkv,
    const float* __restrict__ qw, const float* __restrict__ kw,
    const float* __restrict__ ct, const float* __restrict__ st,
    unsigned short* __restrict__ Qh, unsigned short* __restrict__ Kh,
    unsigned short* __restrict__ VT) {
  if (blockIdx.x >= 12288) {
    // ---- V transpose path: vbid = [b][hk][stile(32)][dt(4)] ----
    __shared__ __align__(16) unsigned short tile[64][72];  // 144B rows
    int vbid = blockIdx.x - 12288;
    int dt = vbid & 3, stile = (vbid >> 2) & 31, hk = (vbid >> 7) & 3, b = vbid >> 9;
    int s0 = stile * 64, d0 = dt * 64;
    int t = threadIdx.x;
#pragma unroll
    for (int i = 0; i < 2; i++) {
      int flat = i * 256 + t;
      int sl = flat >> 3, dc = flat & 7;
      ushort8 v = *(const ushort8*)&qkv[(size_t)(b * 2048 + s0 + sl) * 4096 + 3072 + hk * 256 + d0 + dc * 8];
      *(ushort8*)&tile[sl][dc * 8] = v;
    }
    __syncthreads();
#pragma unroll
    for (int i = 0; i < 2; i++) {
      int flat = i * 256 + t;
      int dl = flat >> 3, sc = flat & 7;
      ushort8 v;
#pragma unroll
      for (int j = 0; j < 8; j++) v[j] = tile[sc * 8 + j][dl];
      int dg = d0 + dl;
      int chg = (s0 >> 3) + sc;
      int swc = chg ^ (dg & 7);
      *(ushort8*)&VT[((size_t)(b * 4 + hk) * 256 + dg) * 2048 + swc * 8] = v;
    }
    return;
  }
  // ---- RMSNorm + RoPE path: one wave per (b,s,head) row ----
  int gwid = (blockIdx.x * 256 + threadIdx.x) >> 6;  // 0 .. 4096*12-1
  int l = threadIdx.x & 63;
  int head = gwid % 12;
  int bs = gwid / 12;
  int b = bs >> 11, s = bs & 2047;
  bool isq = head < 8;
  int col = isq ? head * 256 : 2048 + (head - 8) * 256;
  const unsigned short* src = qkv + (size_t)bs * 4096 + col;
  int d0 = l * 4;
  ushort4 u = *(const ushort4*)(src + d0);
  float x0 = bf2f(u.x), x1 = bf2f(u.y), x2 = bf2f(u.z), x3 = bf2f(u.w);
  float ss = x0 * x0 + x1 * x1 + x2 * x2 + x3 * x3;
#pragma unroll
  for (int off = 32; off > 0; off >>= 1) ss += __shfl_xor(ss, off);
  float inv = rsqrtf(ss * (1.0f / 256.0f) + 1e-6f);
  const float* wv = isq ? qw : kw;
  float4 w4 = *(const float4*)(wv + d0);
  float y0 = x0 * inv * (1.0f + w4.x);
  float y1 = x1 * inv * (1.0f + w4.y);
  float y2 = x2 * inv * (1.0f + w4.z);
  float y3 = x3 * inv * (1.0f + w4.w);
  int fb = (l & 31) * 4;
  float4 c4 = *(const float4*)(ct + s * 128 + fb);
  float4 s4 = *(const float4*)(st + s * 128 + fb);
  float p0 = __shfl_xor(y0, 32), p1 = __shfl_xor(y1, 32);
  float p2 = __shfl_xor(y2, 32), p3 = __shfl_xor(y3, 32);
  float sg = (l < 32) ? -1.0f : 1.0f;
  float o0 = y0 * c4.x + sg * p0 * s4.x;
  float o1 = y1 * c4.y + sg * p1 * s4.y;
  float o2 = y2 * c4.z + sg * p2 * s4.z;
  float o3 = y3 * c4.w + sg * p3 * s4.w;
  if (isq) {
    o0 *= QSCALE; o1 *= QSCALE; o2 *= QSCALE; o3 *= QSCALE;
    unsigned short* dst = Qh + (((size_t)(b * 8 + head)) * 2048 + s) * 256 + d0;
    ushort4 o; o.x = f2bf(o0); o.y = f2bf(o1); o.z = f2bf(o2); o.w = f2bf(o3);
    *(ushort4*)dst = o;
  } else {
    int hk = head - 8;
    int ch = d0 >> 3;
    int dsw = ((ch ^ (s & 7)) << 3) | (d0 & 7);
    unsigned short* dst = Kh + (((size_t)(b * 4 + hk)) * 2048 + s) * 256 + dsw;
    ushort4 o; o.x = f2bf(o0); o.y = f2bf(o1); o.z = f2bf(o2); o.w = f2bf(o3);
    *(ushort4*)dst = o;
  }
}

// ---------------- windowed flash attention, GQA-paired + double-buffered ----------------
__global__ __launch_bounds__(512) void k_attn(
    const unsigned short* __restrict__ Qh,
    const unsigned short* __restrict__ Kh,
    const unsigned short* __restrict__ VT,
    const int* __restrict__ pos,
    unsigned short* __restrict__ Ao) {
  __shared__ __align__(16) unsigned short Ks[2][64 * 256];
  __shared__ __align__(16) unsigned short Vs[2][256 * 64];
  __shared__ __align__(16) unsigned short Ps[8][16 * 72];
  int bid = blockIdx.x;
  int qt = bid & 31, hk = (bid >> 5) & 3, b = bid >> 7;
  int t = threadIdx.x, w = t >> 6, l = t & 63;
  int lr = l & 15, lk = l >> 4;
  int h = hk * 2 + (w >> 2);
  int q0 = qt * 64, qrow0 = q0 + (w & 3) * 16;
  const unsigned short* qbase = Qh + (((size_t)(b * 8 + h)) * 2048 + (qrow0 + lr)) * 256;
  bf16x8 qf[8];
#pragma unroll
  for (int c = 0; c < 8; c++) qf[c] = *(const bf16x8*)&qbase[c * 32 + lk * 8];
  int pq[4];
#pragma unroll
  for (int r = 0; r < 4; r++) pq[r] = pos[qrow0 + lk * 4 + r];
  float m[4], ll[4];
  f32x4 oacc[16];
  f32x4 zero4 = {0.f, 0.f, 0.f, 0.f};
#pragma unroll
  for (int r = 0; r < 4; r++) { m[r] = -1e30f; ll[r] = 0.0f; }
#pragma unroll
  for (int nd = 0; nd < 16; nd++) oacc[nd] = zero4;
  const char* Kbase = (const char*)(Kh + ((size_t)(b * 4 + hk)) * 2048 * 256);
  const char* Vbase = (const char*)(VT + ((size_t)(b * 4 + hk)) * 256 * 2048);
  int jlo = q0 - 511; if (jlo < 0) jlo = 0; jlo &= ~63;
  const int ntj = ((q0 + 64) - jlo) >> 6;

#define ASTAGE(tj_) do { \
    const int j0_ = jlo + (tj_) * 64; \
    char* kd_ = (char*)Ks[(tj_) & 1]; \
    char* vd_ = (char*)Vs[(tj_) & 1]; \
    _Pragma("unroll") \
    for (int i = 0; i < 4; i++) \
      gload16(Kbase + (size_t)j0_ * 512 + i * 8192 + t * 16, kd_ + i * 8192 + w * 1024); \
    _Pragma("unroll") \
    for (int i = 0; i < 4; i++) { \
      int off_ = i * 8192 + t * 16; \
      int d_ = off_ >> 7, rb_ = off_ & 127; \
      gload16(Vbase + (size_t)d_ * 4096 + j0_ * 2 + rb_, vd_ + i * 8192 + w * 1024); \
    } \
  } while (0)

  ASTAGE(0);
  for (int tj = 0; tj < ntj; ++tj) {
    const int j0 = jlo + tj * 64;
    const char* Kb = (const char*)Ks[tj & 1];
    const char* Vb = (const char*)Vs[tj & 1];
    if (tj + 1 < ntj) {
      ASTAGE(tj + 1);
      asm volatile("s_waitcnt vmcnt(8)" ::: "memory");
    } else {
      asm volatile("s_waitcnt vmcnt(0)" ::: "memory");
    }
    SBAR();
    f32x4 sacc[4];
#pragma unroll
    for (int n = 0; n < 4; n++) sacc[n] = zero4;
    __builtin_amdgcn_s_setprio(1);
#pragma unroll
    for (int n = 0; n < 4; n++) {
      int key = n * 16 + lr;
      int sw = (key & 7) << 4;
#pragma unroll
      for (int c = 0; c < 8; c++) {
        bf16x8 kf = *(const bf16x8*)(Kb + key * 512 + ((c * 64 + lk * 16) ^ sw));
        sacc[n] = __builtin_amdgcn_mfma_f32_16x16x32_bf16(qf[c], kf, sacc[n], 0, 0, 0);
      }
    }
    __builtin_amdgcn_s_setprio(0);
    int pk[4];
#pragma unroll
    for (int n = 0; n < 4; n++) pk[n] = pos[j0 + n * 16 + lr];
#pragma unroll
    for (int n = 0; n < 4; n++)
#pragma unroll
      for (int r = 0; r < 4; r++) {
        int dq = pq[r] - pk[n];
        if (!(dq >= 0 && dq < 512)) sacc[n][r] = -1e30f;
      }
    float tm[4], rs[4], mn[4], corr[4];
#pragma unroll
    for (int r = 0; r < 4; r++)
      tm[r] = fmaxf(fmaxf(sacc[0][r], sacc[1][r]), fmaxf(sacc[2][r], sacc[3][r]));
#pragma unroll
    for (int d = 1; d < 16; d <<= 1)
#pragma unroll
      for (int r = 0; r < 4; r++) tm[r] = fmaxf(tm[r], __shfl_xor(tm[r], d));
#pragma unroll
    for (int r = 0; r < 4; r++) {
      mn[r] = fmaxf(m[r], tm[r]);
      corr[r] = exp2f(m[r] - mn[r]);
      rs[r] = 0.f;
    }
#pragma unroll
    for (int n = 0; n < 4; n++)
#pragma unroll
      for (int r = 0; r < 4; r++) {
        float sv = sacc[n][r];
        float p = (sv > -1e29f) ? exp2f(sv - mn[r]) : 0.0f;
        sacc[n][r] = p;
        rs[r] += p;
      }
#pragma unroll
    for (int d = 1; d < 16; d <<= 1)
#pragma unroll
      for (int r = 0; r < 4; r++) rs[r] += __shfl_xor(rs[r], d);
#pragma unroll
    for (int r = 0; r < 4; r++) { ll[r] = ll[r] * corr[r] + rs[r]; m[r] = mn[r]; }
#pragma unroll
    for (int nd = 0; nd < 16; nd++)
#pragma unroll
      for (int r = 0; r < 4; r++) oacc[nd][r] *= corr[r];
#pragma unroll
    for (int n = 0; n < 4; n++)
#pragma unroll
      for (int r = 0; r < 4; r++)
        Ps[w][(lk * 4 + r) * 72 + n * 16 + lr] = f2bf(sacc[n][r]);
#pragma unroll
    for (int c2 = 0; c2 < 2; c2++) {
      bf16x8 pf = *(const bf16x8*)&Ps[w][lr * 72 + c2 * 32 + lk * 8];
      __builtin_amdgcn_s_setprio(1);
#pragma unroll
      for (int nd = 0; nd < 16; nd++) {
        int dr = nd * 16 + lr;
        bf16x8 vf = *(const bf16x8*)(Vb + dr * 128 + ((c2 * 64 + lk * 16) ^ ((dr & 7) << 4)));
        oacc[nd] = __builtin_amdgcn_mfma_f32_16x16x32_bf16(pf, vf, oacc[nd], 0, 0, 0);
      }
      __builtin_amdgcn_s_setprio(0);
    }
    SBAR();
  }
#undef ASTAGE
#pragma unroll
  for (int r = 0; r < 4; r++) ll[r] = 1.0f / ll[r];
#pragma unroll
  for (int nd = 0; nd < 16; nd++)
#pragma unroll
    for (int r = 0; r < 4; r++) {
      float v = oacc[nd][r] * ll[r];
      Ao[((size_t)(b * 2048 + qrow0 + lk * 4 + r)) * 2048 + h * 256 + nd * 16 + lr] = f2bf(v);
    }
}

// ---------------- launch ----------------
// Workspace layout with lifetime-based reuse (peak ≈ 74 MB):
//   region0 [0, 33.55M):  QKV  -> later Ao [0,16.78M) + WoT [16.78M,27.26M)
//   region1 [33.55M, 54.53M): Xb -> later Qh
//   region2 [54.53M, 75.50M): WqT -> later Kh + VT
//   region3 [75.50M, 77.59M): ct, st
extern "C" void kernel_launch(void* const* d_in, const int* in_sizes, int n_in,
                              void* d_out, int out_size, void* d_ws, size_t ws_size,
                              hipStream_t stream) {
  const float* hs   = (const float*)d_in[0];
  const float* wqkv = (const float*)d_in[1];
  const float* wo   = (const float*)d_in[2];
  const float* qnw  = (const float*)d_in[3];
  const float* knw  = (const float*)d_in[4];
  const int*   pos  = (const int*)d_in[5];
  float* out = (float*)d_out;  // reference output dtype is float32

  char* base = (char*)d_ws;
  const size_t OFF_R0 = 0;
  const size_t OFF_R1 = 33554432;
  const size_t OFF_R2 = 54525952;
  const size_t OFF_R3 = 75497472;

  unsigned short* QKV = (unsigned short*)(base + OFF_R0);
  unsigned short* Ao  = (unsigned short*)(base + OFF_R0);
  unsigned short* WoT = (unsigned short*)(base + OFF_R0 + 16777216);
  unsigned short* Xb  = (unsigned short*)(base + OFF_R1);
  unsigned short* Qh  = (unsigned short*)(base + OFF_R1);
  unsigned short* WqT = (unsigned short*)(base + OFF_R2);
  unsigned short* Kh  = (unsigned short*)(base + OFF_R2);
  unsigned short* VT  = (unsigned short*)(base + OFF_R2 + 8388608);
  float* ct = (float*)(base + OFF_R3);
  float* st = (float*)(base + OFF_R3 + 1048576);

  k_prep<<<20480, 256, 0, stream>>>(hs, Xb, 2621440, pos, ct, st, wqkv, WqT);  // cvt + rope + wqkv^T
  k_gemm256<false><<<256, 512, 0, stream>>>(Xb, WqT, QKV, 4096, 4096, 2560);   // Xb, WqT dead after
  k_norm_rope<<<13312, 256, 0, stream>>>(QKV, qnw, knw, ct, st, Qh, Kh, VT);   // + fused V transpose
  k_transpose_w<<<dim3(80, 64), 256, 0, stream>>>(wo, WoT, 2048, 2560);        // WoT over QKV tail
  k_attn<<<256, 512, 0, stream>>>(Qh, Kh, VT, pos, Ao);                        // Ao over QKV head
  k_gemm256<true><<<160, 512, 0, stream>>>(Ao, WoT, out, 4096, 2560, 2048);    // fp32 out
}

// Round 22
// 223.512 us; speedup vs baseline: 1.1151x; 1.0009x over previous
//
#include <hip/hip_runtime.h>
#include <hip/hip_bf16.h>
#include <stdint.h>

// Problem constants
// B=2 S=2048 HID=2560 H=8 HKV=4 D=256 GROUPS=2 window=512
#define QSCALE 0.09016844005555459f  // (1/16) * log2(e)

typedef __attribute__((ext_vector_type(4))) float f32x4;
typedef __attribute__((ext_vector_type(8))) __bf16 bf16x8;
typedef __attribute__((ext_vector_type(8))) unsigned short ushort8;

static __device__ __forceinline__ float bf2f(unsigned short v) {
  union { unsigned u; float f; } x; x.u = ((unsigned)v) << 16; return x.f;
}
static __device__ __forceinline__ unsigned short f2bf(float f) {
  union { float f; unsigned u; } x; x.f = f;
  unsigned r = x.u + 0x7fffu + ((x.u >> 16) & 1u);
  return (unsigned short)(r >> 16);
}
static __device__ __forceinline__ void gload16(const void* g, void* l) {
  __builtin_amdgcn_global_load_lds((const __attribute__((address_space(1))) void*)g,
                                   (__attribute__((address_space(3))) void*)l, 16, 0, 0);
}
#define SBAR() __builtin_amdgcn_s_barrier()

// ---------------- head-of-stream prep, single launch ----------------
// blocks [0,10240): fp32->bf16 cvt of hidden (+ rope table in blocks [0,1024));
// blocks [10240,20480): wqkv transpose fp32[2560][4096] -> bf16[4096][2560];
// blocks [20480,25600) (ONLY when launched with grid 25600, i.e. ws_size
// permits the extended WoT region): wo transpose fp32[2048][2560] ->
// bf16[2560][2048]. All paths have disjoint reads and writes.
__global__ __launch_bounds__(256) void k_prep(const float* __restrict__ in,
                                              unsigned short* __restrict__ out, int n4,
                                              const int* __restrict__ pos,
                                              float* __restrict__ ct,
                                              float* __restrict__ st,
                                              const float* __restrict__ w_in,
                                              unsigned short* __restrict__ w_out,
                                              const float* __restrict__ wo_in,
                                              unsigned short* __restrict__ wo_out) {
  if (blockIdx.x >= 20480) {
    // ---- wo transpose path: R=2048 rows, C=2560 cols ----
    __shared__ float tile[32][33];
    int tb = blockIdx.x - 20480;           // [0, 5120)
    int c0 = (tb % 80) * 32, r0 = (tb / 80) * 32;
    int tx = threadIdx.x & 31, ty = threadIdx.x >> 5;
#pragma unroll
    for (int i = 0; i < 4; i++)
      tile[ty + 8*i][tx] = wo_in[(size_t)(r0 + ty + 8*i) * 2560 + c0 + tx];
    __syncthreads();
#pragma unroll
    for (int i = 0; i < 4; i++)
      wo_out[(size_t)(c0 + ty + 8*i) * 2048 + r0 + tx] = f2bf(tile[tx][ty + 8*i]);
    return;
  }
  if (blockIdx.x >= 10240) {
    // ---- wqkv transpose path: R=2560 rows, C=4096 cols ----
    __shared__ float tile[32][33];
    int tbid = blockIdx.x - 10240;
    int c0 = (tbid & 127) * 32, r0 = (tbid >> 7) * 32;
    int tx = threadIdx.x & 31, ty = threadIdx.x >> 5;
#pragma unroll
    for (int i = 0; i < 4; i++)
      tile[ty + 8*i][tx] = w_in[(size_t)(r0 + ty + 8*i) * 4096 + c0 + tx];
    __syncthreads();
#pragma unroll
    for (int i = 0; i < 4; i++)
      w_out[(size_t)(c0 + ty + 8*i) * 2560 + r0 + tx] = f2bf(tile[tx][ty + 8*i]);
    return;
  }
  int i = blockIdx.x * 256 + threadIdx.x;
  if (blockIdx.x < 1024) {                  // rope table: S*128 = 262144 entries
    int idx = i;
    int s = idx >> 7, j = idx & 127;
    float inv = exp2f((float)j * (-13.287712379549449f / 128.0f));  // 10000^(-j/128)
    float ang = (float)pos[s] * inv;
    float sv, cv;
    sincosf(ang, &sv, &cv);
    ct[idx] = cv; st[idx] = sv;
  }
  if (i >= n4) return;
  float4 v = ((const float4*)in)[i];
  ushort4 o; o.x = f2bf(v.x); o.y = f2bf(v.y); o.z = f2bf(v.z); o.w = f2bf(v.w);
  ((ushort4*)out)[i] = o;
}

// ---------------- transpose fp32 [R][C] -> bf16 [C][R] (wo fallback path) ----------------
__global__ __launch_bounds__(256) void k_transpose_w(const float* __restrict__ in,
                                                     unsigned short* __restrict__ out,
                                                     int R, int C) {
  __shared__ float tile[32][33];
  int c0 = blockIdx.x * 32, r0 = blockIdx.y * 32;
  int tx = threadIdx.x & 31, ty = threadIdx.x >> 5;  // 32 x 8
#pragma unroll
  for (int i = 0; i < 4; i++)
    tile[ty + 8*i][tx] = in[(size_t)(r0 + ty + 8*i) * C + c0 + tx];
  __syncthreads();
#pragma unroll
  for (int i = 0; i < 4; i++)
    out[(size_t)(c0 + ty + 8*i) * R + r0 + tx] = f2bf(tile[tx][ty + 8*i]);
}

// ---------------- 256x256 bf16 GEMM (r10 structure — best measured, FINAL) ----------------
// BK=32, ring of 4 LDS slots (128KB), 8 waves (2Mx4N), counted vmcnt(8) (never
// 0 mid-loop), ONE raw s_barrier per K-step, setprio around the 32-MFMA cluster.
// Ledger: RAW: entering step kt, tile kt in LDS for ALL waves (tail of kt-1 did
// vmcnt(8) + SBAR). WAR: stage(kt+3) -> slot (kt-1)&3; readers were step kt-1's
// ds_reads, complete before its MFMA (lgkm) which precedes the tail SBAR.
// Bank swizzle (verified 0-conflict): chunk ^= (row>>1)&3, inverse-swizzled
// GLOBAL source + swizzled ds_read (rule #21). Requires nt % 4 == 0, nt >= 8.
template <bool F32OUT>
__global__ __launch_bounds__(512, 1) void k_gemm256(const unsigned short* __restrict__ A,
                                                    const unsigned short* __restrict__ Bt,
                                                    void* __restrict__ Cm,
                                                    int M, int N, int K) {
  __shared__ __align__(16) unsigned short ldsA[4][8192];  // 4 slots x [256][32] bf16 (swizzled)
  __shared__ __align__(16) unsigned short ldsB[4][8192];
  const int nbn = N >> 8;
  int bid = blockIdx.x;
  int nwg = gridDim.x;
  if ((nwg & 7) == 0) {                    // XCD-aware swizzle (bijective: nwg%8==0)
    int cpx = nwg >> 3;
    bid = (bid & 7) * cpx + (bid >> 3);
  }
  const int bm = bid / nbn, bn = bid % nbn;
  const int tid = threadIdx.x;
  const int w = tid >> 6, l = tid & 63;
  const int wm = w >> 2, wn = w & 3;
  const int lr = l & 15, lk = l >> 4;
  const int nt = K >> 5;                   // BK = 32; nt % 4 == 0, nt >= 8

  const int rL = tid >> 2;
  const int swc = ((tid & 3) ^ ((tid >> 3) & 3)) << 3;
  const unsigned short* Ag = A + (size_t)(bm * 256 + rL) * K + swc;
  const unsigned short* Bg = Bt + (size_t)(bn * 256 + rL) * K + swc;
  const int ldsoff = w * 512;
  const int wb = ((lk ^ ((lr >> 1) & 3)) << 3);
  const int arow0 = wm * 128 + lr;
  const int brow0 = wn * 64 + lr;

  f32x4 acc[8][4] = {};

#define STAGE_A(kt_, s_) do { \
    gload16(Ag + (size_t)(kt_) * 32,                    (char*)&ldsA[s_][ldsoff]); \
    gload16(Ag + (size_t)(kt_) * 32 + (size_t)128 * K,  (char*)&ldsA[s_][4096 + ldsoff]); } while (0)
#define STAGE_B(kt_, s_) do { \
    gload16(Bg + (size_t)(kt_) * 32,                    (char*)&ldsB[s_][ldsoff]); \
    gload16(Bg + (size_t)(kt_) * 32 + (size_t)128 * K,  (char*)&ldsB[s_][4096 + ldsoff]); } while (0)

#define KSTEP(kt_, S_, PF_, VMC_, TAILBAR_) do { \
    bf16x8 af[8], bf[4]; \
    _Pragma("unroll") \
    for (int i = 0; i < 8; ++i) \
      af[i] = *(const bf16x8*)&ldsA[S_][((arow0 + i * 16) << 5) + wb]; \
    _Pragma("unroll") \
    for (int j = 0; j < 4; ++j) \
      bf[j] = *(const bf16x8*)&ldsB[S_][((brow0 + j * 16) << 5) + wb]; \
    if (PF_) { STAGE_A((kt_) + 3, ((S_) + 3) & 3); STAGE_B((kt_) + 3, ((S_) + 3) & 3); } \
    __builtin_amdgcn_s_setprio(1); \
    _Pragma("unroll") \
    for (int i = 0; i < 8; ++i) \
      _Pragma("unroll") \
      for (int j = 0; j < 4; ++j) \
        acc[i][j] = __builtin_amdgcn_mfma_f32_16x16x32_bf16(af[i], bf[j], acc[i][j], 0, 0, 0); \
    __builtin_amdgcn_s_setprio(0); \
    if ((VMC_) == 8)      { asm volatile("s_waitcnt vmcnt(8)" ::: "memory"); } \
    else if ((VMC_) == 4) { asm volatile("s_waitcnt vmcnt(4)" ::: "memory"); } \
    else if ((VMC_) == 0) { asm volatile("s_waitcnt vmcnt(0)" ::: "memory"); } \
    if (TAILBAR_) SBAR(); \
  } while (0)

  STAGE_A(0, 0); STAGE_B(0, 0);
  STAGE_A(1, 1); STAGE_B(1, 1);
  STAGE_A(2, 2); STAGE_B(2, 2);
  asm volatile("s_waitcnt vmcnt(8)" ::: "memory");
  SBAR();

  const int ng = nt >> 2;
  for (int g = 0; g < ng - 1; ++g) {
    const int kt0 = g << 2;
    KSTEP(kt0 + 0, 0, true, 8, true);
    KSTEP(kt0 + 1, 1, true, 8, true);
    KSTEP(kt0 + 2, 2, true, 8, true);
    KSTEP(kt0 + 3, 3, true, 8, true);
  }
  {
    const int kt0 = nt - 4;
    KSTEP(kt0 + 0, 0, true, 8, true);
    KSTEP(kt0 + 1, 1, false, 4, true);
    KSTEP(kt0 + 2, 2, false, 0, true);
    KSTEP(kt0 + 3, 3, false, -1, false);
  }
#undef KSTEP
#undef STAGE_A
#undef STAGE_B

#pragma unroll
  for (int i = 0; i < 8; ++i)
#pragma unroll
    for (int j = 0; j < 4; ++j) {
      int row = bm * 256 + wm * 128 + i * 16 + lk * 4;
      int col = bn * 256 + wn * 64 + j * 16 + lr;
#pragma unroll
      for (int r = 0; r < 4; ++r) {
        if constexpr (F32OUT)
          ((float*)Cm)[(size_t)(row + r) * N + col] = acc[i][j][r];
        else
          ((unsigned short*)Cm)[(size_t)(row + r) * N + col] = f2bf(acc[i][j][r]);
      }
    }
}

// ---------------- fused RMSNorm+RoPE (Q,K) + V transpose, single launch ----------------
__global__ __launch_bounds__(256) void k_norm_rope(
    const unsigned short* __restrict__ qkv,
    const float* __restrict__ qw, const float* __restrict__ kw,
    const float* __restrict__ ct, const float* __restrict__ st,
    unsigned short* __restrict__ Qh, unsigned short* __restrict__ Kh,
    unsigned short* __restrict__ VT) {
  if (blockIdx.x >= 12288) {
    // ---- V transpose path: vbid = [b][hk][stile(32)][dt(4)] ----
    __shared__ __align__(16) unsigned short tile[64][72];  // 144B rows
    int vbid = blockIdx.x - 12288;
    int dt = vbid & 3, stile = (vbid >> 2) & 31, hk = (vbid >> 7) & 3, b = vbid >> 9;
    int s0 = stile * 64, d0 = dt * 64;
    int t = threadIdx.x;
#pragma unroll
    for (int i = 0; i < 2; i++) {
      int flat = i * 256 + t;
      int sl = flat >> 3, dc = flat & 7;
      ushort8 v = *(const ushort8*)&qkv[(size_t)(b * 2048 + s0 + sl) * 4096 + 3072 + hk * 256 + d0 + dc * 8];
      *(ushort8*)&tile[sl][dc * 8] = v;
    }
    __syncthreads();
#pragma unroll
    for (int i = 0; i < 2; i++) {
      int flat = i * 256 + t;
      int dl = flat >> 3, sc = flat & 7;
      ushort8 v;
#pragma unroll
      for (int j = 0; j < 8; j++) v[j] = tile[sc * 8 + j][dl];
      int dg = d0 + dl;
      int chg = (s0 >> 3) + sc;
      int swc = chg ^ (dg & 7);
      *(ushort8*)&VT[((size_t)(b * 4 + hk) * 256 + dg) * 2048 + swc * 8] = v;
    }
    return;
  }
  // ---- RMSNorm + RoPE path: one wave per (b,s,head) row ----
  int gwid = (blockIdx.x * 256 + threadIdx.x) >> 6;  // 0 .. 4096*12-1
  int l = threadIdx.x & 63;
  int head = gwid % 12;
  int bs = gwid / 12;
  int b = bs >> 11, s = bs & 2047;
  bool isq = head < 8;
  int col = isq ? head * 256 : 2048 + (head - 8) * 256;
  const unsigned short* src = qkv + (size_t)bs * 4096 + col;
  int d0 = l * 4;
  ushort4 u = *(const ushort4*)(src + d0);
  float x0 = bf2f(u.x), x1 = bf2f(u.y), x2 = bf2f(u.z), x3 = bf2f(u.w);
  float ss = x0 * x0 + x1 * x1 + x2 * x2 + x3 * x3;
#pragma unroll
  for (int off = 32; off > 0; off >>= 1) ss += __shfl_xor(ss, off);
  float inv = rsqrtf(ss * (1.0f / 256.0f) + 1e-6f);
  const float* wv = isq ? qw : kw;
  float4 w4 = *(const float4*)(wv + d0);
  float y0 = x0 * inv * (1.0f + w4.x);
  float y1 = x1 * inv * (1.0f + w4.y);
  float y2 = x2 * inv * (1.0f + w4.z);
  float y3 = x3 * inv * (1.0f + w4.w);
  int fb = (l & 31) * 4;
  float4 c4 = *(const float4*)(ct + s * 128 + fb);
  float4 s4 = *(const float4*)(st + s * 128 + fb);
  float p0 = __shfl_xor(y0, 32), p1 = __shfl_xor(y1, 32);
  float p2 = __shfl_xor(y2, 32), p3 = __shfl_xor(y3, 32);
  float sg = (l < 32) ? -1.0f : 1.0f;
  float o0 = y0 * c4.x + sg * p0 * s4.x;
  float o1 = y1 * c4.y + sg * p1 * s4.y;
  float o2 = y2 * c4.z + sg * p2 * s4.z;
  float o3 = y3 * c4.w + sg * p3 * s4.w;
  if (isq) {
    o0 *= QSCALE; o1 *= QSCALE; o2 *= QSCALE; o3 *= QSCALE;
    unsigned short* dst = Qh + (((size_t)(b * 8 + head)) * 2048 + s) * 256 + d0;
    ushort4 o; o.x = f2bf(o0); o.y = f2bf(o1); o.z = f2bf(o2); o.w = f2bf(o3);
    *(ushort4*)dst = o;
  } else {
    int hk = head - 8;
    int ch = d0 >> 3;
    int dsw = ((ch ^ (s & 7)) << 3) | (d0 & 7);
    unsigned short* dst = Kh + (((size_t)(b * 4 + hk)) * 2048 + s) * 256 + dsw;
    ushort4 o; o.x = f2bf(o0); o.y = f2bf(o1); o.z = f2bf(o2); o.w = f2bf(o3);
    *(ushort4*)dst = o;
  }
}

// ---------------- windowed flash attention, GQA-paired + double-buffered ----------------
__global__ __launch_bounds__(512) void k_attn(
    const unsigned short* __restrict__ Qh,
    const unsigned short* __restrict__ Kh,
    const unsigned short* __restrict__ VT,
    const int* __restrict__ pos,
    unsigned short* __restrict__ Ao) {
  __shared__ __align__(16) unsigned short Ks[2][64 * 256];
  __shared__ __align__(16) unsigned short Vs[2][256 * 64];
  __shared__ __align__(16) unsigned short Ps[8][16 * 72];
  int bid = blockIdx.x;
  int qt = bid & 31, hk = (bid >> 5) & 3, b = bid >> 7;
  int t = threadIdx.x, w = t >> 6, l = t & 63;
  int lr = l & 15, lk = l >> 4;
  int h = hk * 2 + (w >> 2);
  int q0 = qt * 64, qrow0 = q0 + (w & 3) * 16;
  const unsigned short* qbase = Qh + (((size_t)(b * 8 + h)) * 2048 + (qrow0 + lr)) * 256;
  bf16x8 qf[8];
#pragma unroll
  for (int c = 0; c < 8; c++) qf[c] = *(const bf16x8*)&qbase[c * 32 + lk * 8];
  int pq[4];
#pragma unroll
  for (int r = 0; r < 4; r++) pq[r] = pos[qrow0 + lk * 4 + r];
  float m[4], ll[4];
  f32x4 oacc[16];
  f32x4 zero4 = {0.f, 0.f, 0.f, 0.f};
#pragma unroll
  for (int r = 0; r < 4; r++) { m[r] = -1e30f; ll[r] = 0.0f; }
#pragma unroll
  for (int nd = 0; nd < 16; nd++) oacc[nd] = zero4;
  const char* Kbase = (const char*)(Kh + ((size_t)(b * 4 + hk)) * 2048 * 256);
  const char* Vbase = (const char*)(VT + ((size_t)(b * 4 + hk)) * 256 * 2048);
  int jlo = q0 - 511; if (jlo < 0) jlo = 0; jlo &= ~63;
  const int ntj = ((q0 + 64) - jlo) >> 6;

#define ASTAGE(tj_) do { \
    const int j0_ = jlo + (tj_) * 64; \
    char* kd_ = (char*)Ks[(tj_) & 1]; \
    char* vd_ = (char*)Vs[(tj_) & 1]; \
    _Pragma("unroll") \
    for (int i = 0; i < 4; i++) \
      gload16(Kbase + (size_t)j0_ * 512 + i * 8192 + t * 16, kd_ + i * 8192 + w * 1024); \
    _Pragma("unroll") \
    for (int i = 0; i < 4; i++) { \
      int off_ = i * 8192 + t * 16; \
      int d_ = off_ >> 7, rb_ = off_ & 127; \
      gload16(Vbase + (size_t)d_ * 4096 + j0_ * 2 + rb_, vd_ + i * 8192 + w * 1024); \
    } \
  } while (0)

  ASTAGE(0);
  for (int tj = 0; tj < ntj; ++tj) {
    const int j0 = jlo + tj * 64;
    const char* Kb = (const char*)Ks[tj & 1];
    const char* Vb = (const char*)Vs[tj & 1];
    if (tj + 1 < ntj) {
      ASTAGE(tj + 1);
      asm volatile("s_waitcnt vmcnt(8)" ::: "memory");
    } else {
      asm volatile("s_waitcnt vmcnt(0)" ::: "memory");
    }
    SBAR();
    f32x4 sacc[4];
#pragma unroll
    for (int n = 0; n < 4; n++) sacc[n] = zero4;
    __builtin_amdgcn_s_setprio(1);
#pragma unroll
    for (int n = 0; n < 4; n++) {
      int key = n * 16 + lr;
      int sw = (key & 7) << 4;
#pragma unroll
      for (int c = 0; c < 8; c++) {
        bf16x8 kf = *(const bf16x8*)(Kb + key * 512 + ((c * 64 + lk * 16) ^ sw));
        sacc[n] = __builtin_amdgcn_mfma_f32_16x16x32_bf16(qf[c], kf, sacc[n], 0, 0, 0);
      }
    }
    __builtin_amdgcn_s_setprio(0);
    int pk[4];
#pragma unroll
    for (int n = 0; n < 4; n++) pk[n] = pos[j0 + n * 16 + lr];
#pragma unroll
    for (int n = 0; n < 4; n++)
#pragma unroll
      for (int r = 0; r < 4; r++) {
        int dq = pq[r] - pk[n];
        if (!(dq >= 0 && dq < 512)) sacc[n][r] = -1e30f;
      }
    float tm[4], rs[4], mn[4], corr[4];
#pragma unroll
    for (int r = 0; r < 4; r++)
      tm[r] = fmaxf(fmaxf(sacc[0][r], sacc[1][r]), fmaxf(sacc[2][r], sacc[3][r]));
#pragma unroll
    for (int d = 1; d < 16; d <<= 1)
#pragma unroll
      for (int r = 0; r < 4; r++) tm[r] = fmaxf(tm[r], __shfl_xor(tm[r], d));
#pragma unroll
    for (int r = 0; r < 4; r++) {
      mn[r] = fmaxf(m[r], tm[r]);
      corr[r] = exp2f(m[r] - mn[r]);
      rs[r] = 0.f;
    }
#pragma unroll
    for (int n = 0; n < 4; n++)
#pragma unroll
      for (int r = 0; r < 4; r++) {
        float sv = sacc[n][r];
        float p = (sv > -1e29f) ? exp2f(sv - mn[r]) : 0.0f;
        sacc[n][r] = p;
        rs[r] += p;
      }
#pragma unroll
    for (int d = 1; d < 16; d <<= 1)
#pragma unroll
      for (int r = 0; r < 4; r++) rs[r] += __shfl_xor(rs[r], d);
#pragma unroll
    for (int r = 0; r < 4; r++) { ll[r] = ll[r] * corr[r] + rs[r]; m[r] = mn[r]; }
#pragma unroll
    for (int nd = 0; nd < 16; nd++)
#pragma unroll
      for (int r = 0; r < 4; r++) oacc[nd][r] *= corr[r];
#pragma unroll
    for (int n = 0; n < 4; n++)
#pragma unroll
      for (int r = 0; r < 4; r++)
        Ps[w][(lk * 4 + r) * 72 + n * 16 + lr] = f2bf(sacc[n][r]);
#pragma unroll
    for (int c2 = 0; c2 < 2; c2++) {
      bf16x8 pf = *(const bf16x8*)&Ps[w][lr * 72 + c2 * 32 + lk * 8];
      __builtin_amdgcn_s_setprio(1);
#pragma unroll
      for (int nd = 0; nd < 16; nd++) {
        int dr = nd * 16 + lr;
        bf16x8 vf = *(const bf16x8*)(Vb + dr * 128 + ((c2 * 64 + lk * 16) ^ ((dr & 7) << 4)));
        oacc[nd] = __builtin_amdgcn_mfma_f32_16x16x32_bf16(pf, vf, oacc[nd], 0, 0, 0);
      }
      __builtin_amdgcn_s_setprio(0);
    }
    SBAR();
  }
#undef ASTAGE
#pragma unroll
  for (int r = 0; r < 4; r++) ll[r] = 1.0f / ll[r];
#pragma unroll
  for (int nd = 0; nd < 16; nd++)
#pragma unroll
    for (int r = 0; r < 4; r++) {
      float v = oacc[nd][r] * ll[r];
      Ao[((size_t)(b * 2048 + qrow0 + lk * 4 + r)) * 2048 + h * 256 + nd * 16 + lr] = f2bf(v);
    }
}

// ---------------- launch ----------------
// Workspace layout with lifetime-based reuse:
//   region0 [0, 33.55M):  QKV  -> later Ao [0,16.78M) (+ WoT tail in fallback)
//   region1 [33.55M, 54.53M): Xb -> later Qh
//   region2 [54.53M, 75.50M): WqT -> later Kh + VT
//   region3 [75.50M, 77.59M): ct, st
//   region4 [77.59M, 88.08M): WoT (ONLY if ws_size >= 88080384; else WoT
//     aliases region0 tail and is produced after QKV's last reader)
extern "C" void kernel_launch(void* const* d_in, const int* in_sizes, int n_in,
                              void* d_out, int out_size, void* d_ws, size_t ws_size,
                              hipStream_t stream) {
  const float* hs   = (const float*)d_in[0];
  const float* wqkv = (const float*)d_in[1];
  const float* wo   = (const float*)d_in[2];
  const float* qnw  = (const float*)d_in[3];
  const float* knw  = (const float*)d_in[4];
  const int*   pos  = (const int*)d_in[5];
  float* out = (float*)d_out;  // reference output dtype is float32

  char* base = (char*)d_ws;
  const size_t OFF_R0 = 0;
  const size_t OFF_R1 = 33554432;
  const size_t OFF_R2 = 54525952;
  const size_t OFF_R3 = 75497472;
  const size_t OFF_R4 = 77594624;                 // extended WoT region
  const bool wofuse = (ws_size >= OFF_R4 + 10485760);

  unsigned short* QKV = (unsigned short*)(base + OFF_R0);
  unsigned short* Ao  = (unsigned short*)(base + OFF_R0);
  unsigned short* WoT = wofuse ? (unsigned short*)(base + OFF_R4)
                               : (unsigned short*)(base + OFF_R0 + 16777216);
  unsigned short* Xb  = (unsigned short*)(base + OFF_R1);
  unsigned short* Qh  = (unsigned short*)(base + OFF_R1);
  unsigned short* WqT = (unsigned short*)(base + OFF_R2);
  unsigned short* Kh  = (unsigned short*)(base + OFF_R2);
  unsigned short* VT  = (unsigned short*)(base + OFF_R2 + 8388608);
  float* ct = (float*)(base + OFF_R3);
  float* st = (float*)(base + OFF_R3 + 1048576);

  // prep: cvt + rope + wqkv^T (+ wo^T when the extended region exists)
  k_prep<<<wofuse ? 25600 : 20480, 256, 0, stream>>>(hs, Xb, 2621440, pos, ct, st,
                                                     wqkv, WqT, wo, WoT);
  k_gemm256<false><<<256, 512, 0, stream>>>(Xb, WqT, QKV, 4096, 4096, 2560);   // Xb, WqT dead after
  k_norm_rope<<<13312, 256, 0, stream>>>(QKV, qnw, knw, ct, st, Qh, Kh, VT);   // + fused V transpose
  if (!wofuse)
    k_transpose_w<<<dim3(80, 64), 256, 0, stream>>>(wo, WoT, 2048, 2560);      // WoT over QKV tail
  k_attn<<<256, 512, 0, stream>>>(Qh, Kh, VT, pos, Ao);                        // Ao over QKV head
  k_gemm256<true><<<160, 512, 0, stream>>>(Ao, WoT, out, 4096, 2560, 2048);    // fp32 out
}